// Round 20
// baseline (133.483 us; speedup 1.0000x reference)
//
#include <hip/hip_runtime.h>

#define NUMA 5
#define NCLS 80
#define AL 85          // 80 + 4 + 1
#define HW 361         // 19*19
#define NBOX 1805      // 5*361
#define NBATCH 128
#define NPAD 2048
#define K2T 256
#define MCAP 1024      // cap on num_obj for fast path (expected ~902 +/- 21)
#define NCHUNK 16      // MCAP / 64
#define NSPLIT 8       // sup blocks per image (128 global waves -> <=1 tile/wave)

// ---- d_ws layout ----
#define WS_NUMOBJ_OFF 0                                  // int32 [128]
#define WS_ORDER_OFF  512                                // u16   [128][2048]
#define WS_SOBJ_OFF   (512 + NBATCH * NPAD * 2)          // f32   [128][2048]
#define WS_NEEDED     ((size_t)(WS_SOBJ_OFF + NBATCH * NPAD * 4))   // ~1.5 MB
#define WS_SUP_OFF    WS_NEEDED                          // u64 [128][16][1024]
#define WS_DROW_OFF   (WS_SUP_OFF + (size_t)NBATCH * NCHUNK * MCAP * 8)
#define WS_NEEDED2    (WS_DROW_OFF + (size_t)NBATCH * NCHUNK * 64 * 8)  // ~19.3 MB
#define WS_DETW_OFF   WS_NEEDED2                         // f32 [128][1805][7]
#define WS_NEEDED3    (WS_DETW_OFF + (size_t)NBATCH * NBOX * 7 * 4)     // ~25.8 MB

// Exact-division-compare constant: MID = (0.45f + pred(0.45f))/2 exactly.
// RN32(inter/denom) >= 0.45f  <=>  fma64(denom, MID, -inter) <= 0 (exact sign)
#define MID_CONST (30198987.0 / 67108864.0)

__device__ __forceinline__ unsigned long long bcast64(unsigned long long v, int t) {
    unsigned lo = (unsigned)__builtin_amdgcn_readlane((int)(unsigned)v, t);
    unsigned hi = (unsigned)__builtin_amdgcn_readlane((int)(unsigned)(v >> 32), t);
    return ((unsigned long long)hi << 32) | (unsigned long long)lo;
}

__device__ __forceinline__ float bcastf(float v, int t) {
    return __uint_as_float(
        (unsigned)__builtin_amdgcn_readlane((int)__float_as_uint(v), t));
}

// Reference-exact suppression test (iou >= 0.45f under IEEE f32 ref arith).
__device__ __forceinline__ bool supp_test(float4 qj, float aj, float4 qi, float ai) {
#pragma clang fp contract(off)
    float iw = fmaxf(fminf(qj.z, qi.z) - fmaxf(qj.x, qi.x), 0.0f);
    float ih = fmaxf(fminf(qj.w, qi.w) - fmaxf(qj.y, qi.y), 0.0f);
    float inter = iw * ih;
    float denom = (aj + ai) - inter;
    return fma((double)denom, MID_CONST, -(double)inter) <= 0.0;
}

// ---------------------------------------------------------------------------
// Kernel 1: decode.  pred [B, 425, 19, 19] -> det [B, 1805, 7] written to out
// ---------------------------------------------------------------------------
__global__ __launch_bounds__(256) void decode_kernel(
    const float* __restrict__ pred,
    const float* __restrict__ anchors,
    float* __restrict__ det)
{
#pragma clang fp contract(off)
    int id = blockIdx.x * blockDim.x + threadIdx.x;
    if (id >= NBATCH * NBOX) return;
    int b = id / NBOX;
    int r = id - b * NBOX;
    int a = r / HW;
    int s = r - a * HW;
    int ci = s % 19;
    int cj = s / 19;

    const float* base = pred + ((size_t)(b * (NUMA * AL) + a * AL) * HW + s);
    float tx  = base[0 * HW];
    float ty  = base[1 * HW];
    float tw  = base[2 * HW];
    float th  = base[3 * HW];
    float obj = base[4 * HW];

    float cmax = base[5 * HW];
    int karg = 0;
#pragma unroll 4
    for (int k = 1; k < NCLS; ++k) {
        float c = base[(5 + k) * HW];
        if (c > cmax) { cmax = c; karg = k; }
    }

    float bx = (tx + (float)ci) / 19.0f;
    float by = (ty + (float)cj) / 19.0f;
    float aw = anchors[2 * a];
    float ah = anchors[2 * a + 1];
    float bw = expf(tw) * (aw / 19.0f);
    float bh = expf(th) * (ah / 19.0f);
    float prob = cmax * obj;
    float cid  = (float)karg;

    float* o = det + (size_t)(b * NBOX + r) * 7;
    o[0] = obj; o[1] = bx; o[2] = by; o[3] = bw; o[4] = bh; o[5] = cid; o[6] = prob;
}

// ---------------------------------------------------------------------------
// Kernel 2 (tier 3): top-K sort. obj values read COALESCED from pred.
// Only the predicate subset (cnt ~ 902) is sorted; detws rows [cnt,1024)
// and all sobj beyond cnt are zeroed.
// ---------------------------------------------------------------------------
__global__ __launch_bounds__(1024) void sortc_kernel(
    const float* __restrict__ pred,
    const float* __restrict__ det,
    float* __restrict__ sobj_g,
    int* __restrict__ nobj_g,
    float* __restrict__ detws)
{
    __shared__ unsigned long long keys[NPAD];
    __shared__ int c0s[16], c1s[16];
    __shared__ int ex0s[16], ex1s[16];
    __shared__ int cnt_sh, totA_sh;
    const int b = blockIdx.x;
    const int tid = threadIdx.x;
    const int lane = tid & 63;
    const int wv = tid >> 6;
    const float* detb = det + (size_t)b * NBOX * 7;
    const float* predb = pred + (size_t)b * (NUMA * AL) * HW;

    int r0 = tid;
    int r1 = tid + 1024;
    int a0 = r0 / HW, s0 = r0 - a0 * HW;
    float obj0 = predb[(a0 * AL + 4) * HW + s0];
    float obj1 = -1.0f;
    if (r1 < NBOX) {
        int a1 = r1 / HW, s1 = r1 - a1 * HW;
        obj1 = predb[(a1 * AL + 4) * HW + s1];
    }
    bool p0 = obj0 > 0.5f;
    bool p1 = (r1 < NBOX) && (obj1 > 0.5f);
    unsigned long long m0 = __ballot(p0);
    unsigned long long m1 = __ballot(p1);
    if (lane == 0) { c0s[wv] = __builtin_popcountll(m0); c1s[wv] = __builtin_popcountll(m1); }
    __syncthreads();
    if (tid == 0) {
        int acc = 0;
        for (int w = 0; w < 16; ++w) { ex0s[w] = acc; acc += c0s[w]; }
        totA_sh = acc;
        for (int w = 0; w < 16; ++w) { ex1s[w] = acc; acc += c1s[w]; }
        cnt_sh = acc;
    }
    __syncthreads();
    const int cnt = cnt_sh;
    unsigned long long ltm = (1ull << lane) - 1ull;

    if (cnt <= MCAP) {
        if (p0) {
            int pos = ex0s[wv] + __builtin_popcountll(m0 & ltm);
            keys[pos] = ((unsigned long long)__float_as_uint(obj0) << 32)
                      | (unsigned long long)(2047 - r0);
        }
        if (p1) {
            int pos = ex1s[wv] + __builtin_popcountll(m1 & ltm);
            keys[pos] = ((unsigned long long)__float_as_uint(obj1) << 32)
                      | (unsigned long long)(2047 - r1);
        }
        if (tid >= cnt) keys[tid] = 0ull;
        __syncthreads();

        for (unsigned k = 2; k <= 1024; k <<= 1) {
            for (unsigned j = k >> 1; j > 0; j >>= 1) {
                unsigned idx = tid;
                unsigned ixj = idx ^ j;
                if (ixj > idx) {
                    unsigned long long av = keys[idx], bv = keys[ixj];
                    bool up = ((idx & k) == 0);
                    if (up ? (av < bv) : (av > bv)) { keys[idx] = bv; keys[ixj] = av; }
                }
                __syncthreads();
            }
        }

        unsigned long long kk = keys[tid];
        float* dst = detws + ((size_t)b * NBOX + tid) * 7;
        if (tid < cnt) {
            int idx = 2047 - (int)(unsigned)(kk & 0xffffffffu);
            sobj_g[b * NPAD + tid] = __uint_as_float((unsigned)(kk >> 32));
            const float* src = detb + idx * 7;
#pragma unroll
            for (int q = 0; q < 7; ++q) dst[q] = src[q];
        } else {
            sobj_g[b * NPAD + tid] = 0.0f;
#pragma unroll
            for (int q = 0; q < 7; ++q) dst[q] = 0.0f;
        }
        sobj_g[b * NPAD + 1024 + tid] = 0.0f;
        if (tid == 0) nobj_g[b] = cnt;
    } else {
        // full-sort fallback (statistically unreachable)
        keys[r0] = ((unsigned long long)__float_as_uint(obj0) << 32)
                 | (unsigned long long)(2047 - r0);
        keys[r1] = (r1 < NBOX)
                 ? (((unsigned long long)__float_as_uint(obj1) << 32)
                    | (unsigned long long)(2047 - r1))
                 : 0ull;
        __syncthreads();
        for (unsigned k = 2; k <= NPAD; k <<= 1) {
            for (unsigned j = k >> 1; j > 0; j >>= 1) {
                for (unsigned idx = tid; idx < NPAD; idx += 1024) {
                    unsigned ixj = idx ^ j;
                    if (ixj > idx) {
                        unsigned long long av = keys[idx], bv = keys[ixj];
                        bool up = ((idx & k) == 0);
                        if (up ? (av < bv) : (av > bv)) { keys[idx] = bv; keys[ixj] = av; }
                    }
                }
                __syncthreads();
            }
        }
        for (int r = tid; r < NBOX; r += 1024) {
            unsigned long long kk = keys[r];
            int idx = 2047 - (int)(unsigned)(kk & 0xffffffffu);
            sobj_g[b * NPAD + r] = __uint_as_float((unsigned)(kk >> 32));
            const float* src = detb + idx * 7;
            float* dst = detws + ((size_t)b * NBOX + r) * 7;
#pragma unroll
            for (int q = 0; q < 7; ++q) dst[q] = src[q];
        }
        for (int r = NBOX + tid; r < NPAD; r += 1024) sobj_g[b * NPAD + r] = 0.0f;
        if (tid == 0) nobj_g[b] = cnt;
    }
}

// ---------------------------------------------------------------------------
// Kernel (fallback tiers): per-image stable bitonic sort (desc by obj).
// ---------------------------------------------------------------------------
__global__ __launch_bounds__(1024) void sort_kernel(
    const float* __restrict__ det,
    unsigned short* __restrict__ order_g,
    float* __restrict__ sobj_g,
    int* __restrict__ nobj_g)
{
    __shared__ unsigned long long keys[NPAD];
    __shared__ int cnt_sh;
    const int b = blockIdx.x;
    const int tid = threadIdx.x;
    const float* detb = det + (size_t)b * NBOX * 7;

    for (int n = tid; n < NPAD; n += 1024) {
        keys[n] = (n < NBOX)
            ? (((unsigned long long)__float_as_uint(detb[n * 7]) << 32)
               | (unsigned long long)(2047 - n))
            : 0ull;
    }
    if (tid == 0) cnt_sh = 0;
    __syncthreads();

    for (unsigned k = 2; k <= NPAD; k <<= 1) {
        for (unsigned j = k >> 1; j > 0; j >>= 1) {
            for (unsigned idx = tid; idx < NPAD; idx += 1024) {
                unsigned ixj = idx ^ j;
                if (ixj > idx) {
                    unsigned long long av = keys[idx], bv = keys[ixj];
                    bool up = ((idx & k) == 0);
                    if (up ? (av < bv) : (av > bv)) { keys[idx] = bv; keys[ixj] = av; }
                }
            }
            __syncthreads();
        }
    }

    int cnt = 0;
    for (int r = tid; r < NBOX; r += 1024) {
        unsigned long long kk = keys[r];
        int idx = 2047 - (int)(unsigned)(kk & 0xffffffffu);
        order_g[b * NPAD + r] = (unsigned short)idx;
        float ob = __uint_as_float((unsigned)(kk >> 32));
        sobj_g[b * NPAD + r] = ob;
        cnt += (ob > 0.5f) ? 1 : 0;
    }
    atomicAdd(&cnt_sh, cnt);
    __syncthreads();
    if (tid == 0) nobj_g[b] = cnt_sh;
}

// ---------------------------------------------------------------------------
// Kernel 3: suppression-matrix build, REGISTER-BROADCAST version (no LDS).
// Grid = 128 * NSPLIT blocks; each wave takes <= ~1 tile. Per tile each lane
// holds exactly two boxes in registers: qj (its column box in chunk c2) and
// qc (its copy of chunk cc); per-t broadcast is 5 v_readlane (SGPR results
// are free VALU operands) instead of ~18cyc of LDS reads. Off-diag mask
// accumulation batched: 8 compile-time shifts + one u64 shift per 8 t's.
// Pad rows (rank >= cnt) are all-zero boxes -> supp always false vs real.
// ---------------------------------------------------------------------------
__global__ __launch_bounds__(1024) void sup_kernel(
    const int* __restrict__ nobj_g,
    unsigned long long* __restrict__ sup_g,
    unsigned long long* __restrict__ drow_g,
    const float* __restrict__ detws)
{
#pragma clang fp contract(off)
    const int bb = blockIdx.x;
    const int b = bb / NSPLIT;
    const int part = bb - b * NSPLIT;
    const int tid = threadIdx.x;
    const int lane = tid & 63;
    const int wv = tid >> 6;
    const int num_obj = nobj_g[b];
    if (num_obj > MCAP) return;                          // fallback handles
    const int M = num_obj;
    const int Mc = (M + 63) >> 6;                        // active chunks
    const int Atiles = Mc * (Mc + 1) / 2;                // active tiles
    const int NW = 16 * NSPLIT;                          // global waves/image

    const int gw = part * 16 + wv;                       // 0..NW-1
    const int ks = (gw * Atiles) / NW;
    const int ke = ((gw + 1) * Atiles) / NW;
    for (int k = ks; k < ke; ++k) {
        int c2 = 0;
        while ((c2 + 1) * (c2 + 2) / 2 <= k) ++c2;       // tile -> (c2, cc<=c2)
        int cc = k - c2 * (c2 + 1) / 2;
        // lane's own (column) box in chunk c2
        const float* srcj = detws + ((size_t)b * NBOX + c2 * 64 + lane) * 7;
        float bxj = srcj[1], byj = srcj[2], bwj = srcj[3], bhj = srcj[4];
        float4 qj = make_float4(bxj - 0.5f * bwj, byj - 0.5f * bhj,
                                bxj + 0.5f * bwj, byj + 0.5f * bhj);
        float aj = bwj * bhj;
        unsigned long long w = 0ull;
        if (cc == c2) {
            unsigned long long myrow = 0ull;
            for (int t = 0; t < 64; ++t) {
                float4 qt = make_float4(bcastf(qj.x, t), bcastf(qj.y, t),
                                        bcastf(qj.z, t), bcastf(qj.w, t));
                float at = bcastf(aj, t);
                bool supp = supp_test(qj, aj, qt, at) && (t < lane);
                unsigned long long bb2 = __ballot(supp);
                w |= supp ? (1ull << t) : 0ull;
                if (lane == t) myrow = bb2;
            }
            drow_g[((size_t)b * NCHUNK + cc) * 64 + lane] = myrow;
        } else {
            // lane's copy of chunk cc (broadcast source)
            const float* srcc = detws + ((size_t)b * NBOX + cc * 64 + lane) * 7;
            float bxc = srcc[1], byc = srcc[2], bwc = srcc[3], bhc = srcc[4];
            float4 qc = make_float4(bxc - 0.5f * bwc, byc - 0.5f * bhc,
                                    bxc + 0.5f * bwc, byc + 0.5f * bhc);
            float ac = bwc * bhc;
            for (int t0 = 0; t0 < 64; t0 += 8) {
                unsigned batch = 0u;
#pragma unroll
                for (int u = 0; u < 8; ++u) {
                    int t = t0 + u;
                    float4 qt = make_float4(bcastf(qc.x, t), bcastf(qc.y, t),
                                            bcastf(qc.z, t), bcastf(qc.w, t));
                    float at = bcastf(ac, t);
                    bool supp = supp_test(qj, aj, qt, at);
                    batch |= supp ? (1u << u) : 0u;
                }
                w |= (unsigned long long)batch << t0;
            }
        }
        sup_g[((size_t)b * NCHUNK + cc) * MCAP + c2 * 64 + lane] = w;
    }
}

// ---------------------------------------------------------------------------
// Kernel 4 (tier 3): fused scan + epilogue. 256 threads/image. 4 waves stage
// only the ACTIVE Mc chunks of SUP (+ DROW + sobj) into LDS; wave 0 scans;
// all waves run the epilogue (rows >= num_obj write zeros without reading).
// ---------------------------------------------------------------------------
__global__ __launch_bounds__(256) void scanepi3_kernel(
    float* __restrict__ det,
    const float* __restrict__ detws,
    const float* __restrict__ sobj_g,
    const int* __restrict__ nobj_g,
    const unsigned long long* __restrict__ sup_g,
    const unsigned long long* __restrict__ drow_g)
{
#pragma clang fp contract(off)
    __shared__ unsigned long long SUPL[NCHUNK][MCAP];    // 128 KB
    __shared__ unsigned long long DR[NCHUNK][64];        // 8 KB
    __shared__ float sobj_l[NPAD];                       // 8 KB
    const int b = blockIdx.x;
    const int tid = threadIdx.x;
    const int lane = tid & 63;
    float* detb = det + (size_t)b * NBOX * 7;
    const float* dws = detws + (size_t)b * NBOX * 7;
    const int num_obj = nobj_g[b];
    const int M = (num_obj < MCAP) ? num_obj : MCAP;
    const int Mc = (M + 63) >> 6;

#pragma unroll
    for (int c = 0; c < 8; ++c)
        sobj_l[tid + c * 256] = sobj_g[b * NPAD + tid + c * 256];

    if (num_obj <= MCAP) {
        const unsigned long long* supb = sup_g + (size_t)b * NCHUNK * MCAP;
        // stage only the active chunks (4*Mc strips of 256 u64)
        for (int i = 0; i < 4 * Mc; ++i)
            ((unsigned long long*)SUPL)[tid + i * 256] = supb[tid + i * 256];
#pragma unroll
        for (int i = 0; i < 4; ++i)
            ((unsigned long long*)DR)[tid + i * 256] =
                drow_g[(size_t)b * NCHUNK * 64 + tid + i * 256];
        __syncthreads();

        if (tid < 64) {
            unsigned rm = 0u;                  // bit c = my box in chunk c dead
            for (int c = 0; c < NCHUNK && c * 64 < M; ++c) {
                int rem_in = M - c * 64;
                unsigned long long cmask =
                    (rem_in >= 64) ? ~0ull : ((1ull << rem_in) - 1ull);
                unsigned long long deadw = __ballot((rm >> c) & 1u);
                unsigned long long rowreg = DR[c][lane];
                unsigned long long rem = cmask & ~deadw;
                const unsigned long long rem0 = rem;
                unsigned long long S = 0ull;   // survivors of chunk c
                while (rem) {
                    int t = (int)__builtin_ctzll(rem);
                    S |= (1ull << t);
                    unsigned long long row_t = bcast64(rowreg, t);
                    rem &= ~row_t;
                    rem &= ~(1ull << t);
                }
                unsigned long long deadnew = rem0 & ~S;
                rm |= (unsigned)((deadnew >> lane) & 1ull) << c;
                for (int c2 = c + 1; c2 < NCHUNK && c2 * 64 < M; ++c2) {
                    unsigned long long w2 = SUPL[c][c2 * 64 + lane];
                    rm |= ((w2 & S) != 0ull) ? (1u << c2) : 0u;
                }
            }
#pragma unroll
            for (int c2 = 0; c2 < NCHUNK; ++c2) {
                int j = c2 * 64 + lane;
                if (j < M && ((rm >> c2) & 1u)) sobj_l[j] = 0.0f;
            }
        }
        __syncthreads();
    } else {
        __syncthreads();
        // fallback: serial greedy over coalesced sorted rows
        for (int i = 0; i < num_obj; ++i) {
            if (sobj_l[i] > 0.01f) {
                const float* ri = dws + i * 7;
                float bxi = ri[1], byi = ri[2], bwi = ri[3], bhi = ri[4];
                float xi1 = bxi - 0.5f * bwi, xi2 = bxi + 0.5f * bwi;
                float yi1 = byi - 0.5f * bhi, yi2 = byi + 0.5f * bhi;
                float ai = bwi * bhi;
                for (int j = i + 1 + tid; j < num_obj; j += 256) {
                    const float* rj = dws + j * 7;
                    float bxj = rj[1], byj = rj[2], bwj = rj[3], bhj = rj[4];
                    float x1j = bxj - 0.5f * bwj, x2j = bxj + 0.5f * bwj;
                    float y1j = byj - 0.5f * bhj, y2j = byj + 0.5f * bhj;
                    float aj = bwj * bhj;
                    float iw = fmaxf(fminf(x2j, xi2) - fmaxf(x1j, xi1), 0.0f);
                    float ih = fmaxf(fminf(y2j, yi2) - fmaxf(y1j, yi1), 0.0f);
                    float inter = iw * ih;
                    float iou = inter / ((aj + ai) - inter);
                    if (iou >= 0.45f) sobj_l[j] = 0.0f;
                }
            }
            __syncthreads();
        }
    }

    // --- epilogue: rows < num_obj from detws; rows >= num_obj are zeros ---
#pragma unroll
    for (int c = 0; c < 8; ++c) {
        int r = tid + c * 256;
        if (r < NBOX) {
            float* o = detb + r * 7;
            if (r < num_obj) {
                const float* src = dws + r * 7;
                float obj = src[0], bx = src[1], by = src[2], bw = src[3];
                float bh = src[4], cid = src[5], prob = src[6];
                float s = sobj_l[r];
                bool keep = (s > 0.01f) && (r != num_obj - 1);
                float p = prob * ((prob > 0.1f) ? 1.0f : 0.0f);
                bool fin = keep && (p > 0.01f) && (bw * bw > 0.0004f);
                float m = fin ? 1.0f : 0.0f;
                o[0] = obj * m; o[1] = bx * m; o[2] = by * m; o[3] = bw * m;
                o[4] = bh * m; o[5] = cid * m; o[6] = p * m;
            } else {
                o[0] = 0.0f; o[1] = 0.0f; o[2] = 0.0f; o[3] = 0.0f;
                o[4] = 0.0f; o[5] = 0.0f; o[6] = 0.0f;
            }
        }
    }
}

// ---------------------------------------------------------------------------
// Tier-1 fallback (1.5MB <= ws < 25.8MB): monolithic two-phase NMS + epi.
// ---------------------------------------------------------------------------
__global__ __launch_bounds__(1024, 1) void nms4_kernel(
    const float* __restrict__ det,
    const unsigned short* __restrict__ order_g,
    float* __restrict__ sobj_g,
    const int* __restrict__ nobj_g)
{
#pragma clang fp contract(off)
    __shared__ float4 QS[MCAP];
    __shared__ float  AS[MCAP];
    __shared__ unsigned long long SUP[NCHUNK][MCAP];
    __shared__ unsigned long long DROW[NCHUNK][64];
    const int b = blockIdx.x;
    const int tid = threadIdx.x;
    const int lane = tid & 63;
    const int wv = tid >> 6;
    const float* detb = det + (size_t)b * NBOX * 7;
    const unsigned short* ord = order_g + b * NPAD;
    float* sobj = sobj_g + b * NPAD;
    const int num_obj = nobj_g[b];
    const int M = (num_obj < MCAP) ? num_obj : MCAP;

    if (num_obj <= MCAP) {
        {
            const float* row = detb + (int)ord[tid] * 7;
            float bx = row[1], by = row[2], bw = row[3], bh = row[4];
            QS[tid] = make_float4(bx - 0.5f * bw, by - 0.5f * bh,
                                  bx + 0.5f * bw, by + 0.5f * bh);
            AS[tid] = bw * bh;
        }
        __syncthreads();

        for (int k = wv; k < 136; k += 16) {
            int c2 = 0;
            while ((c2 + 1) * (c2 + 2) / 2 <= k) ++c2;
            int cc = k - c2 * (c2 + 1) / 2;
            if (c2 * 64 < M) {
                int j = c2 * 64 + lane;
                float4 qj = QS[j];
                float  aj = AS[j];
                unsigned long long w = 0ull;
                if (cc == c2) {
                    unsigned long long myrow = 0ull;
                    for (int t = 0; t < 64; ++t) {
                        bool supp = supp_test(qj, aj, QS[cc * 64 + t], AS[cc * 64 + t])
                                    && (t < lane);
                        unsigned long long bb = __ballot(supp);
                        w |= supp ? (1ull << t) : 0ull;
                        if (lane == t) myrow = bb;
                    }
                    DROW[cc][lane] = myrow;
                } else {
#pragma unroll 8
                    for (int t = 0; t < 64; ++t) {
                        bool supp = supp_test(qj, aj, QS[cc * 64 + t], AS[cc * 64 + t]);
                        w |= supp ? (1ull << t) : 0ull;
                    }
                }
                SUP[cc][j] = w;
            }
        }
        __syncthreads();

        if (wv == 0) {
            unsigned rm = 0u;
            for (int c = 0; c < NCHUNK && c * 64 < M; ++c) {
                int rem_in = M - c * 64;
                unsigned long long cmask =
                    (rem_in >= 64) ? ~0ull : ((1ull << rem_in) - 1ull);
                unsigned long long deadw = __ballot((rm >> c) & 1u);
                unsigned long long rowreg = DROW[c][lane];
                unsigned long long rem = cmask & ~deadw;
                const unsigned long long rem0 = rem;
                unsigned long long S = 0ull;
                while (rem) {
                    int t = (int)__builtin_ctzll(rem);
                    S |= (1ull << t);
                    unsigned long long row_t = bcast64(rowreg, t);
                    rem &= ~row_t;
                    rem &= ~(1ull << t);
                }
                unsigned long long deadnew = rem0 & ~S;
                rm |= (unsigned)((deadnew >> lane) & 1ull) << c;
                for (int c2 = c + 1; c2 < NCHUNK && c2 * 64 < M; ++c2) {
                    unsigned long long w2 = SUP[c][c2 * 64 + lane];
                    rm |= ((w2 & S) != 0ull) ? (1u << c2) : 0u;
                }
            }
            for (int c2 = 0; c2 < NCHUNK; ++c2) {
                int j = c2 * 64 + lane;
                if (j < M && ((rm >> c2) & 1u)) sobj[j] = 0.0f;
            }
        }
    } else {
        for (int i = 0; i < num_obj; ++i) {
            if (sobj[i] > 0.01f) {
                const float* ri = detb + (int)ord[i] * 7;
                float bxi = ri[1], byi = ri[2], bwi = ri[3], bhi = ri[4];
                float xi1 = bxi - 0.5f * bwi, xi2 = bxi + 0.5f * bwi;
                float yi1 = byi - 0.5f * bhi, yi2 = byi + 0.5f * bhi;
                float ai = bwi * bhi;
                for (int j = i + 1 + tid; j < num_obj; j += 1024) {
                    const float* rj = detb + (int)ord[j] * 7;
                    float bxj = rj[1], byj = rj[2], bwj = rj[3], bhj = rj[4];
                    float x1j = bxj - 0.5f * bwj, x2j = bxj + 0.5f * bwj;
                    float y1j = byj - 0.5f * bhj, y2j = byj + 0.5f * bhj;
                    float aj = bwj * bhj;
                    float iw = fmaxf(fminf(x2j, xi2) - fmaxf(x1j, xi1), 0.0f);
                    float ih = fmaxf(fminf(y2j, yi2) - fmaxf(y1j, yi1), 0.0f);
                    float inter = iw * ih;
                    float iou = inter / ((aj + ai) - inter);
                    if (iou >= 0.45f) sobj[j] = 0.0f;
                }
            }
            __syncthreads();
        }
    }
}

__global__ __launch_bounds__(256) void epi_kernel(
    float* __restrict__ det,
    const unsigned short* __restrict__ order_g,
    const float* __restrict__ sobj_g,
    const int* __restrict__ nobj_g)
{
#pragma clang fp contract(off)
    const int b = blockIdx.x;
    const int tid = threadIdx.x;
    float* detb = det + (size_t)b * NBOX * 7;
    const unsigned short* ord = order_g + b * NPAD;
    const float* sobj = sobj_g + b * NPAD;
    const int num_obj = nobj_g[b];

    float v0[8], v1[8], v2[8], v3[8], v4[8], v5[8], v6[8], msk[8];
#pragma unroll
    for (int c = 0; c < 8; ++c) {
        int r = tid + c * 256;
        if (r < NBOX) {
            const float* row = detb + (int)ord[r] * 7;
            float obj = row[0], bx = row[1], by = row[2], bw = row[3];
            float bh = row[4], cid = row[5], prob = row[6];
            bool keep = (r < num_obj) && (sobj[r] > 0.01f) && (r != num_obj - 1);
            float p = prob * ((prob > 0.1f) ? 1.0f : 0.0f);
            bool fin = keep && (p > 0.01f) && (bw * bw > 0.0004f);
            v0[c] = obj; v1[c] = bx; v2[c] = by; v3[c] = bw; v4[c] = bh;
            v5[c] = cid; v6[c] = p;
            msk[c] = fin ? 1.0f : 0.0f;
        }
    }
    __syncthreads();
#pragma unroll
    for (int c = 0; c < 8; ++c) {
        int r = tid + c * 256;
        if (r < NBOX) {
            float* o = detb + r * 7;
            o[0] = v0[c] * msk[c];
            o[1] = v1[c] * msk[c];
            o[2] = v2[c] * msk[c];
            o[3] = v3[c] * msk[c];
            o[4] = v4[c] * msk[c];
            o[5] = v5[c] * msk[c];
            o[6] = v6[c] * msk[c];
        }
    }
}

// ---------------------------------------------------------------------------
// Last-resort monolithic kernel (ws < WS_NEEDED).
// ---------------------------------------------------------------------------
__global__ __launch_bounds__(K2T, 1) void nms_kernel(float* __restrict__ det)
{
#pragma clang fp contract(off)
    __shared__ alignas(16) unsigned long long keys[NPAD];
    __shared__ float s_obj[NBOX];
    __shared__ unsigned short order[NBOX];
    __shared__ int num_obj_sh;

    const int b = blockIdx.x;
    const int tid = threadIdx.x;
    float* detb = det + (size_t)b * NBOX * 7;

    for (int n = tid; n < NPAD; n += K2T) {
        if (n < NBOX) {
            unsigned ob = __float_as_uint(detb[n * 7 + 0]);
            keys[n] = ((unsigned long long)ob << 32) | (unsigned long long)(2047 - n);
        } else keys[n] = 0ull;
    }
    if (tid == 0) num_obj_sh = 0;
    __syncthreads();

    for (unsigned k = 2; k <= NPAD; k <<= 1) {
        for (unsigned j = k >> 1; j > 0; j >>= 1) {
            for (unsigned idx = tid; idx < NPAD; idx += K2T) {
                unsigned ixj = idx ^ j;
                if (ixj > idx) {
                    unsigned long long av = keys[idx], bv = keys[ixj];
                    bool up = ((idx & k) == 0);
                    if (up ? (av < bv) : (av > bv)) { keys[idx] = bv; keys[ixj] = av; }
                }
            }
            __syncthreads();
        }
    }

    int cnt = 0;
    for (int r = tid; r < NBOX; r += K2T) {
        unsigned long long kk = keys[r];
        order[r] = (unsigned short)(2047u - (unsigned)(kk & 0xffffffffu));
        float ob = __uint_as_float((unsigned)(kk >> 32));
        s_obj[r] = ob;
        cnt += (ob > 0.5f) ? 1 : 0;
    }
    atomicAdd(&num_obj_sh, cnt);
    __syncthreads();
    const int num_obj = num_obj_sh;

    for (int i = 0; i < num_obj; ++i) {
        if (s_obj[i] > 0.01f) {
            const float* ri = detb + (int)order[i] * 7;
            float bxi = ri[1], byi = ri[2], bwi = ri[3], bhi = ri[4];
            float xi1 = bxi - 0.5f * bwi, xi2 = bxi + 0.5f * bwi;
            float yi1 = byi - 0.5f * bhi, yi2 = byi + 0.5f * bhi;
            float ai = bwi * bhi;
            for (int j = i + 1 + tid; j < num_obj; j += K2T) {
                const float* rj = detb + (int)order[j] * 7;
                float bxj = rj[1], byj = rj[2], bwj = rj[3], bhj = rj[4];
                float x1j = bxj - 0.5f * bwj, x2j = bxj + 0.5f * bwj;
                float y1j = byj - 0.5f * bhj, y2j = byj + 0.5f * bhj;
                float aj = bwj * bhj;
                float iw = fmaxf(fminf(x2j, xi2) - fmaxf(x1j, xi1), 0.0f);
                float ih = fmaxf(fminf(y2j, yi2) - fmaxf(y1j, yi1), 0.0f);
                float inter = iw * ih;
                float iou = inter / ((aj + ai) - inter);
                if (iou >= 0.45f) s_obj[j] = 0.0f;
            }
        }
        __syncthreads();
    }

    float v0[8], v1[8], v2[8], v3[8], v4[8], v5[8], v6[8], msk[8];
#pragma unroll
    for (int c = 0; c < 8; ++c) {
        int r = tid + c * K2T;
        if (r < NBOX) {
            const float* row = detb + (int)order[r] * 7;
            float obj = row[0], bx = row[1], by = row[2], bw = row[3];
            float bh = row[4], cid = row[5], prob = row[6];
            bool keep = (r < num_obj) && (s_obj[r] > 0.01f) && (r != num_obj - 1);
            float p = prob * ((prob > 0.1f) ? 1.0f : 0.0f);
            bool fin = keep && (p > 0.01f) && (bw * bw > 0.0004f);
            v0[c] = obj; v1[c] = bx; v2[c] = by; v3[c] = bw; v4[c] = bh;
            v5[c] = cid; v6[c] = p;
            msk[c] = fin ? 1.0f : 0.0f;
        }
    }
    __syncthreads();
#pragma unroll
    for (int c = 0; c < 8; ++c) {
        int r = tid + c * K2T;
        if (r < NBOX) {
            float* o = detb + r * 7;
            o[0] = v0[c] * msk[c]; o[1] = v1[c] * msk[c]; o[2] = v2[c] * msk[c];
            o[3] = v3[c] * msk[c]; o[4] = v4[c] * msk[c]; o[5] = v5[c] * msk[c];
            o[6] = v6[c] * msk[c];
        }
    }
}

extern "C" void kernel_launch(void* const* d_in, const int* in_sizes, int n_in,
                              void* d_out, int out_size, void* d_ws, size_t ws_size,
                              hipStream_t stream)
{
    const float* pred    = (const float*)d_in[0];
    const float* anchors = (const float*)d_in[1];
    float* out = (float*)d_out;

    int total = NBATCH * NBOX;
    int blocks = (total + 255) / 256;
    decode_kernel<<<blocks, 256, 0, stream>>>(pred, anchors, out);

    if (ws_size >= WS_NEEDED3) {
        char* ws = (char*)d_ws;
        int*                nobj  = (int*)(ws + WS_NUMOBJ_OFF);
        float*              sobj  = (float*)(ws + WS_SOBJ_OFF);
        unsigned long long* sup   = (unsigned long long*)(ws + WS_SUP_OFF);
        unsigned long long* drow  = (unsigned long long*)(ws + WS_DROW_OFF);
        float*              detw  = (float*)(ws + WS_DETW_OFF);
        sortc_kernel<<<NBATCH, 1024, 0, stream>>>(pred, out, sobj, nobj, detw);
        sup_kernel<<<NBATCH * NSPLIT, 1024, 0, stream>>>(nobj, sup, drow, detw);
        scanepi3_kernel<<<NBATCH, 256, 0, stream>>>(out, detw, sobj, nobj, sup, drow);
    } else if (ws_size >= WS_NEEDED) {
        char* ws = (char*)d_ws;
        int*            nobj  = (int*)(ws + WS_NUMOBJ_OFF);
        unsigned short* order = (unsigned short*)(ws + WS_ORDER_OFF);
        float*          sobj  = (float*)(ws + WS_SOBJ_OFF);
        sort_kernel<<<NBATCH, 1024, 0, stream>>>(out, order, sobj, nobj);
        nms4_kernel<<<NBATCH, 1024, 0, stream>>>(out, order, sobj, nobj);
        epi_kernel<<<NBATCH, 256, 0, stream>>>(out, order, sobj, nobj);
    } else {
        nms_kernel<<<NBATCH, K2T, 0, stream>>>(out);
    }
}

// Round 21
// 113.520 us; speedup vs baseline: 1.1759x; 1.1759x over previous
//
#include <hip/hip_runtime.h>

#define NUMA 5
#define NCLS 80
#define AL 85          // 80 + 4 + 1
#define HW 361         // 19*19
#define NBOX 1805      // 5*361
#define NBATCH 128
#define NPAD 2048
#define K2T 256
#define MCAP 1024      // cap on num_obj for fast path (expected ~902 +/- 21)
#define NCHUNK 16      // MCAP / 64
#define NSPLIT 8       // sup blocks per image

// ---- d_ws layout ----
#define WS_NUMOBJ_OFF 0                                  // int32 [128]
#define WS_ORDER_OFF  512                                // u16   [128][2048]
#define WS_SOBJ_OFF   (512 + NBATCH * NPAD * 2)          // f32   [128][2048]
#define WS_NEEDED     ((size_t)(WS_SOBJ_OFF + NBATCH * NPAD * 4))   // ~1.5 MB
#define WS_SUP_OFF    WS_NEEDED                          // u64 [128][16][1024]
#define WS_DROW_OFF   (WS_SUP_OFF + (size_t)NBATCH * NCHUNK * MCAP * 8)
#define WS_NEEDED2    (WS_DROW_OFF + (size_t)NBATCH * NCHUNK * 64 * 8)  // ~19.3 MB
#define WS_DETW_OFF   WS_NEEDED2                         // f32 [128][1805][7]
#define WS_NEEDED3    (WS_DETW_OFF + (size_t)NBATCH * NBOX * 7 * 4)     // ~25.8 MB

// Exact-division-compare constant: MID = (0.45f + pred(0.45f))/2 exactly.
// RN32(inter/denom) >= 0.45f  <=>  fma64(denom, MID, -inter) <= 0 (exact sign)
#define MID_CONST (30198987.0 / 67108864.0)

__device__ __forceinline__ unsigned long long bcast64(unsigned long long v, int t) {
    unsigned lo = (unsigned)__builtin_amdgcn_readlane((int)(unsigned)v, t);
    unsigned hi = (unsigned)__builtin_amdgcn_readlane((int)(unsigned)(v >> 32), t);
    return ((unsigned long long)hi << 32) | (unsigned long long)lo;
}

__device__ __forceinline__ unsigned long long shflxor64(unsigned long long v, int j) {
    unsigned lo = __shfl_xor((unsigned)v, j, 64);
    unsigned hi = __shfl_xor((unsigned)(v >> 32), j, 64);
    return ((unsigned long long)hi << 32) | (unsigned long long)lo;
}

// Reference-exact suppression test (iou >= 0.45f under IEEE f32 ref arith).
__device__ __forceinline__ bool supp_test(float4 qj, float aj, float4 qi, float ai) {
#pragma clang fp contract(off)
    float iw = fmaxf(fminf(qj.z, qi.z) - fmaxf(qj.x, qi.x), 0.0f);
    float ih = fmaxf(fminf(qj.w, qi.w) - fmaxf(qj.y, qi.y), 0.0f);
    float inter = iw * ih;
    float denom = (aj + ai) - inter;
    return fma((double)denom, MID_CONST, -(double)inter) <= 0.0;
}

// ---------------------------------------------------------------------------
// Kernel 1: decode.  pred [B, 425, 19, 19] -> det [B, 1805, 7] written to out
// ---------------------------------------------------------------------------
__global__ __launch_bounds__(256) void decode_kernel(
    const float* __restrict__ pred,
    const float* __restrict__ anchors,
    float* __restrict__ det)
{
#pragma clang fp contract(off)
    int id = blockIdx.x * blockDim.x + threadIdx.x;
    if (id >= NBATCH * NBOX) return;
    int b = id / NBOX;
    int r = id - b * NBOX;
    int a = r / HW;
    int s = r - a * HW;
    int ci = s % 19;
    int cj = s / 19;

    const float* base = pred + ((size_t)(b * (NUMA * AL) + a * AL) * HW + s);
    float tx  = base[0 * HW];
    float ty  = base[1 * HW];
    float tw  = base[2 * HW];
    float th  = base[3 * HW];
    float obj = base[4 * HW];

    float cmax = base[5 * HW];
    int karg = 0;
#pragma unroll 4
    for (int k = 1; k < NCLS; ++k) {
        float c = base[(5 + k) * HW];
        if (c > cmax) { cmax = c; karg = k; }
    }

    float bx = (tx + (float)ci) / 19.0f;
    float by = (ty + (float)cj) / 19.0f;
    float aw = anchors[2 * a];
    float ah = anchors[2 * a + 1];
    float bw = expf(tw) * (aw / 19.0f);
    float bh = expf(th) * (ah / 19.0f);
    float prob = cmax * obj;
    float cid  = (float)karg;

    float* o = det + (size_t)(b * NBOX + r) * 7;
    o[0] = obj; o[1] = bx; o[2] = by; o[3] = bw; o[4] = bh; o[5] = cid; o[6] = prob;
}

// ---------------------------------------------------------------------------
// Kernel 2 (tier 3): top-K sort, hybrid shuffle/LDS bitonic.
// obj read coalesced from pred; only the predicate subset (cnt ~ 902) is
// sorted. Keys live in registers; passes with j<64 use __shfl_xor (no
// barrier), only the 10 passes with j>=64 round-trip through LDS.
// ---------------------------------------------------------------------------
__global__ __launch_bounds__(1024) void sortc_kernel(
    const float* __restrict__ pred,
    const float* __restrict__ det,
    float* __restrict__ sobj_g,
    int* __restrict__ nobj_g,
    float* __restrict__ detws)
{
    __shared__ unsigned long long keys[NPAD];
    __shared__ int c0s[16], c1s[16];
    __shared__ int ex0s[16], ex1s[16];
    __shared__ int cnt_sh, totA_sh;
    const int b = blockIdx.x;
    const int tid = threadIdx.x;
    const int lane = tid & 63;
    const int wv = tid >> 6;
    const float* detb = det + (size_t)b * NBOX * 7;
    const float* predb = pred + (size_t)b * (NUMA * AL) * HW;

    int r0 = tid;
    int r1 = tid + 1024;
    int a0 = r0 / HW, s0 = r0 - a0 * HW;
    float obj0 = predb[(a0 * AL + 4) * HW + s0];
    float obj1 = -1.0f;
    if (r1 < NBOX) {
        int a1 = r1 / HW, s1 = r1 - a1 * HW;
        obj1 = predb[(a1 * AL + 4) * HW + s1];
    }
    bool p0 = obj0 > 0.5f;
    bool p1 = (r1 < NBOX) && (obj1 > 0.5f);
    unsigned long long m0 = __ballot(p0);
    unsigned long long m1 = __ballot(p1);
    if (lane == 0) { c0s[wv] = __builtin_popcountll(m0); c1s[wv] = __builtin_popcountll(m1); }
    __syncthreads();
    if (tid == 0) {
        int acc = 0;
        for (int w = 0; w < 16; ++w) { ex0s[w] = acc; acc += c0s[w]; }
        totA_sh = acc;
        for (int w = 0; w < 16; ++w) { ex1s[w] = acc; acc += c1s[w]; }
        cnt_sh = acc;
    }
    __syncthreads();
    const int cnt = cnt_sh;
    unsigned long long ltm = (1ull << lane) - 1ull;

    if (cnt <= MCAP) {
        if (p0) {
            int pos = ex0s[wv] + __builtin_popcountll(m0 & ltm);
            keys[pos] = ((unsigned long long)__float_as_uint(obj0) << 32)
                      | (unsigned long long)(2047 - r0);
        }
        if (p1) {
            int pos = ex1s[wv] + __builtin_popcountll(m1 & ltm);
            keys[pos] = ((unsigned long long)__float_as_uint(obj1) << 32)
                      | (unsigned long long)(2047 - r1);
        }
        if (tid >= cnt) keys[tid] = 0ull;
        __syncthreads();

        // --- hybrid bitonic over 1024 keys, descending; key in register ---
        unsigned long long key = keys[tid];
        for (unsigned k = 2; k <= 1024; k <<= 1) {
            for (unsigned j = k >> 1; j > 0; j >>= 1) {
                unsigned long long other;
                if (j >= 64) {
                    __syncthreads();
                    keys[tid] = key;
                    __syncthreads();
                    other = keys[tid ^ j];
                } else {
                    other = shflxor64(key, (int)j);
                }
                bool lower = ((tid & j) == 0);
                bool up = ((tid & k) == 0);
                bool keepmax = (lower == up);
                unsigned long long mx = (key > other) ? key : other;
                unsigned long long mn = (key > other) ? other : key;
                key = keepmax ? mx : mn;
            }
        }

        // --- outputs directly from register key ---
        float* dst = detws + ((size_t)b * NBOX + tid) * 7;
        if (tid < cnt) {
            int idx = 2047 - (int)(unsigned)(key & 0xffffffffu);
            sobj_g[b * NPAD + tid] = __uint_as_float((unsigned)(key >> 32));
            const float* src = detb + idx * 7;
#pragma unroll
            for (int q = 0; q < 7; ++q) dst[q] = src[q];
        } else {
            sobj_g[b * NPAD + tid] = 0.0f;
#pragma unroll
            for (int q = 0; q < 7; ++q) dst[q] = 0.0f;
        }
        sobj_g[b * NPAD + 1024 + tid] = 0.0f;
        if (tid == 0) nobj_g[b] = cnt;
    } else {
        // full-sort fallback (statistically unreachable)
        keys[r0] = ((unsigned long long)__float_as_uint(obj0) << 32)
                 | (unsigned long long)(2047 - r0);
        keys[r1] = (r1 < NBOX)
                 ? (((unsigned long long)__float_as_uint(obj1) << 32)
                    | (unsigned long long)(2047 - r1))
                 : 0ull;
        __syncthreads();
        for (unsigned k = 2; k <= NPAD; k <<= 1) {
            for (unsigned j = k >> 1; j > 0; j >>= 1) {
                for (unsigned idx = tid; idx < NPAD; idx += 1024) {
                    unsigned ixj = idx ^ j;
                    if (ixj > idx) {
                        unsigned long long av = keys[idx], bv = keys[ixj];
                        bool up = ((idx & k) == 0);
                        if (up ? (av < bv) : (av > bv)) { keys[idx] = bv; keys[ixj] = av; }
                    }
                }
                __syncthreads();
            }
        }
        for (int r = tid; r < NBOX; r += 1024) {
            unsigned long long kk = keys[r];
            int idx = 2047 - (int)(unsigned)(kk & 0xffffffffu);
            sobj_g[b * NPAD + r] = __uint_as_float((unsigned)(kk >> 32));
            const float* src = detb + idx * 7;
            float* dst = detws + ((size_t)b * NBOX + r) * 7;
#pragma unroll
            for (int q = 0; q < 7; ++q) dst[q] = src[q];
        }
        for (int r = NBOX + tid; r < NPAD; r += 1024) sobj_g[b * NPAD + r] = 0.0f;
        if (tid == 0) nobj_g[b] = cnt;
    }
}

// ---------------------------------------------------------------------------
// Kernel (fallback tiers): per-image stable bitonic sort (desc by obj).
// ---------------------------------------------------------------------------
__global__ __launch_bounds__(1024) void sort_kernel(
    const float* __restrict__ det,
    unsigned short* __restrict__ order_g,
    float* __restrict__ sobj_g,
    int* __restrict__ nobj_g)
{
    __shared__ unsigned long long keys[NPAD];
    __shared__ int cnt_sh;
    const int b = blockIdx.x;
    const int tid = threadIdx.x;
    const float* detb = det + (size_t)b * NBOX * 7;

    for (int n = tid; n < NPAD; n += 1024) {
        keys[n] = (n < NBOX)
            ? (((unsigned long long)__float_as_uint(detb[n * 7]) << 32)
               | (unsigned long long)(2047 - n))
            : 0ull;
    }
    if (tid == 0) cnt_sh = 0;
    __syncthreads();

    for (unsigned k = 2; k <= NPAD; k <<= 1) {
        for (unsigned j = k >> 1; j > 0; j >>= 1) {
            for (unsigned idx = tid; idx < NPAD; idx += 1024) {
                unsigned ixj = idx ^ j;
                if (ixj > idx) {
                    unsigned long long av = keys[idx], bv = keys[ixj];
                    bool up = ((idx & k) == 0);
                    if (up ? (av < bv) : (av > bv)) { keys[idx] = bv; keys[ixj] = av; }
                }
            }
            __syncthreads();
        }
    }

    int cnt = 0;
    for (int r = tid; r < NBOX; r += 1024) {
        unsigned long long kk = keys[r];
        int idx = 2047 - (int)(unsigned)(kk & 0xffffffffu);
        order_g[b * NPAD + r] = (unsigned short)idx;
        float ob = __uint_as_float((unsigned)(kk >> 32));
        sobj_g[b * NPAD + r] = ob;
        cnt += (ob > 0.5f) ? 1 : 0;
    }
    atomicAdd(&cnt_sh, cnt);
    __syncthreads();
    if (tid == 0) nobj_g[b] = cnt_sh;
}

// ---------------------------------------------------------------------------
// Kernel 3: suppression-matrix build (round-19 best config: LDS-staged
// boxes, NSPLIT=8 balanced tiles, unroll 8, pure-f64 exact test).
// ---------------------------------------------------------------------------
__global__ __launch_bounds__(1024) void sup_kernel(
    const int* __restrict__ nobj_g,
    unsigned long long* __restrict__ sup_g,
    unsigned long long* __restrict__ drow_g,
    const float* __restrict__ detws)
{
#pragma clang fp contract(off)
    __shared__ float4 QS[MCAP];                          // 16 KB
    __shared__ float  AS[MCAP];                          // 4 KB
    const int bb = blockIdx.x;
    const int b = bb / NSPLIT;
    const int part = bb - b * NSPLIT;
    const int tid = threadIdx.x;
    const int lane = tid & 63;
    const int wv = tid >> 6;
    const int num_obj = nobj_g[b];
    if (num_obj > MCAP) return;                          // fallback handles
    const int M = num_obj;
    const int Mc = (M + 63) >> 6;                        // active chunks
    const int Atiles = Mc * (Mc + 1) / 2;                // active tiles
    const int NW = 16 * NSPLIT;                          // global waves/image

    {
        const float* src = detws + ((size_t)b * NBOX + tid) * 7;   // coalesced
        float bx = src[1], by = src[2], bw = src[3], bh = src[4];
        QS[tid] = make_float4(bx - 0.5f * bw, by - 0.5f * bh,
                              bx + 0.5f * bw, by + 0.5f * bh);
        AS[tid] = bw * bh;
    }
    __syncthreads();

    const int gw = part * 16 + wv;                       // 0..NW-1
    const int ks = (gw * Atiles) / NW;
    const int ke = ((gw + 1) * Atiles) / NW;
    for (int k = ks; k < ke; ++k) {
        int c2 = 0;
        while ((c2 + 1) * (c2 + 2) / 2 <= k) ++c2;       // tile -> (c2, cc<=c2)
        int cc = k - c2 * (c2 + 1) / 2;
        int j = c2 * 64 + lane;
        float4 qj = QS[j];
        float  aj = AS[j];
        unsigned long long w = 0ull;
        if (cc == c2) {
            unsigned long long myrow = 0ull;
            for (int t = 0; t < 64; ++t) {
                bool supp = supp_test(qj, aj, QS[cc * 64 + t], AS[cc * 64 + t])
                            && (t < lane);
                unsigned long long bb2 = __ballot(supp);
                w |= supp ? (1ull << t) : 0ull;
                if (lane == t) myrow = bb2;
            }
            drow_g[((size_t)b * NCHUNK + cc) * 64 + lane] = myrow;
        } else {
#pragma unroll 8
            for (int t = 0; t < 64; ++t) {
                bool supp = supp_test(qj, aj, QS[cc * 64 + t], AS[cc * 64 + t]);
                w |= supp ? (1ull << t) : 0ull;
            }
        }
        sup_g[((size_t)b * NCHUNK + cc) * MCAP + j] = w;
    }
}

// ---------------------------------------------------------------------------
// Kernel 4 (tier 3): fused scan + epilogue. 256 threads/image. 4 waves stage
// only the ACTIVE Mc chunks of SUP (+ DROW + sobj) into LDS; wave 0 scans;
// all waves run the epilogue (rows >= num_obj write zeros without reading).
// ---------------------------------------------------------------------------
__global__ __launch_bounds__(256) void scanepi3_kernel(
    float* __restrict__ det,
    const float* __restrict__ detws,
    const float* __restrict__ sobj_g,
    const int* __restrict__ nobj_g,
    const unsigned long long* __restrict__ sup_g,
    const unsigned long long* __restrict__ drow_g)
{
#pragma clang fp contract(off)
    __shared__ unsigned long long SUPL[NCHUNK][MCAP];    // 128 KB
    __shared__ unsigned long long DR[NCHUNK][64];        // 8 KB
    __shared__ float sobj_l[NPAD];                       // 8 KB
    const int b = blockIdx.x;
    const int tid = threadIdx.x;
    const int lane = tid & 63;
    float* detb = det + (size_t)b * NBOX * 7;
    const float* dws = detws + (size_t)b * NBOX * 7;
    const int num_obj = nobj_g[b];
    const int M = (num_obj < MCAP) ? num_obj : MCAP;
    const int Mc = (M + 63) >> 6;

#pragma unroll
    for (int c = 0; c < 8; ++c)
        sobj_l[tid + c * 256] = sobj_g[b * NPAD + tid + c * 256];

    if (num_obj <= MCAP) {
        const unsigned long long* supb = sup_g + (size_t)b * NCHUNK * MCAP;
        for (int i = 0; i < 4 * Mc; ++i)
            ((unsigned long long*)SUPL)[tid + i * 256] = supb[tid + i * 256];
#pragma unroll
        for (int i = 0; i < 4; ++i)
            ((unsigned long long*)DR)[tid + i * 256] =
                drow_g[(size_t)b * NCHUNK * 64 + tid + i * 256];
        __syncthreads();

        if (tid < 64) {
            unsigned rm = 0u;                  // bit c = my box in chunk c dead
            for (int c = 0; c < NCHUNK && c * 64 < M; ++c) {
                int rem_in = M - c * 64;
                unsigned long long cmask =
                    (rem_in >= 64) ? ~0ull : ((1ull << rem_in) - 1ull);
                unsigned long long deadw = __ballot((rm >> c) & 1u);
                unsigned long long rowreg = DR[c][lane];
                unsigned long long rem = cmask & ~deadw;
                const unsigned long long rem0 = rem;
                unsigned long long S = 0ull;   // survivors of chunk c
                while (rem) {
                    int t = (int)__builtin_ctzll(rem);
                    S |= (1ull << t);
                    unsigned long long row_t = bcast64(rowreg, t);
                    rem &= ~row_t;
                    rem &= ~(1ull << t);
                }
                unsigned long long deadnew = rem0 & ~S;
                rm |= (unsigned)((deadnew >> lane) & 1ull) << c;
                for (int c2 = c + 1; c2 < NCHUNK && c2 * 64 < M; ++c2) {
                    unsigned long long w2 = SUPL[c][c2 * 64 + lane];
                    rm |= ((w2 & S) != 0ull) ? (1u << c2) : 0u;
                }
            }
#pragma unroll
            for (int c2 = 0; c2 < NCHUNK; ++c2) {
                int j = c2 * 64 + lane;
                if (j < M && ((rm >> c2) & 1u)) sobj_l[j] = 0.0f;
            }
        }
        __syncthreads();
    } else {
        __syncthreads();
        // fallback: serial greedy over coalesced sorted rows
        for (int i = 0; i < num_obj; ++i) {
            if (sobj_l[i] > 0.01f) {
                const float* ri = dws + i * 7;
                float bxi = ri[1], byi = ri[2], bwi = ri[3], bhi = ri[4];
                float xi1 = bxi - 0.5f * bwi, xi2 = bxi + 0.5f * bwi;
                float yi1 = byi - 0.5f * bhi, yi2 = byi + 0.5f * bhi;
                float ai = bwi * bhi;
                for (int j = i + 1 + tid; j < num_obj; j += 256) {
                    const float* rj = dws + j * 7;
                    float bxj = rj[1], byj = rj[2], bwj = rj[3], bhj = rj[4];
                    float x1j = bxj - 0.5f * bwj, x2j = bxj + 0.5f * bwj;
                    float y1j = byj - 0.5f * bhj, y2j = byj + 0.5f * bhj;
                    float aj = bwj * bhj;
                    float iw = fmaxf(fminf(x2j, xi2) - fmaxf(x1j, xi1), 0.0f);
                    float ih = fmaxf(fminf(y2j, yi2) - fmaxf(y1j, yi1), 0.0f);
                    float inter = iw * ih;
                    float iou = inter / ((aj + ai) - inter);
                    if (iou >= 0.45f) sobj_l[j] = 0.0f;
                }
            }
            __syncthreads();
        }
    }

    // --- epilogue: rows < num_obj from detws; rows >= num_obj are zeros ---
#pragma unroll
    for (int c = 0; c < 8; ++c) {
        int r = tid + c * 256;
        if (r < NBOX) {
            float* o = detb + r * 7;
            if (r < num_obj) {
                const float* src = dws + r * 7;
                float obj = src[0], bx = src[1], by = src[2], bw = src[3];
                float bh = src[4], cid = src[5], prob = src[6];
                float s = sobj_l[r];
                bool keep = (s > 0.01f) && (r != num_obj - 1);
                float p = prob * ((prob > 0.1f) ? 1.0f : 0.0f);
                bool fin = keep && (p > 0.01f) && (bw * bw > 0.0004f);
                float m = fin ? 1.0f : 0.0f;
                o[0] = obj * m; o[1] = bx * m; o[2] = by * m; o[3] = bw * m;
                o[4] = bh * m; o[5] = cid * m; o[6] = p * m;
            } else {
                o[0] = 0.0f; o[1] = 0.0f; o[2] = 0.0f; o[3] = 0.0f;
                o[4] = 0.0f; o[5] = 0.0f; o[6] = 0.0f;
            }
        }
    }
}

// ---------------------------------------------------------------------------
// Tier-1 fallback (1.5MB <= ws < 25.8MB): monolithic two-phase NMS + epi.
// ---------------------------------------------------------------------------
__global__ __launch_bounds__(1024, 1) void nms4_kernel(
    const float* __restrict__ det,
    const unsigned short* __restrict__ order_g,
    float* __restrict__ sobj_g,
    const int* __restrict__ nobj_g)
{
#pragma clang fp contract(off)
    __shared__ float4 QS[MCAP];
    __shared__ float  AS[MCAP];
    __shared__ unsigned long long SUP[NCHUNK][MCAP];
    __shared__ unsigned long long DROW[NCHUNK][64];
    const int b = blockIdx.x;
    const int tid = threadIdx.x;
    const int lane = tid & 63;
    const int wv = tid >> 6;
    const float* detb = det + (size_t)b * NBOX * 7;
    const unsigned short* ord = order_g + b * NPAD;
    float* sobj = sobj_g + b * NPAD;
    const int num_obj = nobj_g[b];
    const int M = (num_obj < MCAP) ? num_obj : MCAP;

    if (num_obj <= MCAP) {
        {
            const float* row = detb + (int)ord[tid] * 7;
            float bx = row[1], by = row[2], bw = row[3], bh = row[4];
            QS[tid] = make_float4(bx - 0.5f * bw, by - 0.5f * bh,
                                  bx + 0.5f * bw, by + 0.5f * bh);
            AS[tid] = bw * bh;
        }
        __syncthreads();

        for (int k = wv; k < 136; k += 16) {
            int c2 = 0;
            while ((c2 + 1) * (c2 + 2) / 2 <= k) ++c2;
            int cc = k - c2 * (c2 + 1) / 2;
            if (c2 * 64 < M) {
                int j = c2 * 64 + lane;
                float4 qj = QS[j];
                float  aj = AS[j];
                unsigned long long w = 0ull;
                if (cc == c2) {
                    unsigned long long myrow = 0ull;
                    for (int t = 0; t < 64; ++t) {
                        bool supp = supp_test(qj, aj, QS[cc * 64 + t], AS[cc * 64 + t])
                                    && (t < lane);
                        unsigned long long bb = __ballot(supp);
                        w |= supp ? (1ull << t) : 0ull;
                        if (lane == t) myrow = bb;
                    }
                    DROW[cc][lane] = myrow;
                } else {
#pragma unroll 8
                    for (int t = 0; t < 64; ++t) {
                        bool supp = supp_test(qj, aj, QS[cc * 64 + t], AS[cc * 64 + t]);
                        w |= supp ? (1ull << t) : 0ull;
                    }
                }
                SUP[cc][j] = w;
            }
        }
        __syncthreads();

        if (wv == 0) {
            unsigned rm = 0u;
            for (int c = 0; c < NCHUNK && c * 64 < M; ++c) {
                int rem_in = M - c * 64;
                unsigned long long cmask =
                    (rem_in >= 64) ? ~0ull : ((1ull << rem_in) - 1ull);
                unsigned long long deadw = __ballot((rm >> c) & 1u);
                unsigned long long rowreg = DROW[c][lane];
                unsigned long long rem = cmask & ~deadw;
                const unsigned long long rem0 = rem;
                unsigned long long S = 0ull;
                while (rem) {
                    int t = (int)__builtin_ctzll(rem);
                    S |= (1ull << t);
                    unsigned long long row_t = bcast64(rowreg, t);
                    rem &= ~row_t;
                    rem &= ~(1ull << t);
                }
                unsigned long long deadnew = rem0 & ~S;
                rm |= (unsigned)((deadnew >> lane) & 1ull) << c;
                for (int c2 = c + 1; c2 < NCHUNK && c2 * 64 < M; ++c2) {
                    unsigned long long w2 = SUP[c][c2 * 64 + lane];
                    rm |= ((w2 & S) != 0ull) ? (1u << c2) : 0u;
                }
            }
            for (int c2 = 0; c2 < NCHUNK; ++c2) {
                int j = c2 * 64 + lane;
                if (j < M && ((rm >> c2) & 1u)) sobj[j] = 0.0f;
            }
        }
    } else {
        for (int i = 0; i < num_obj; ++i) {
            if (sobj[i] > 0.01f) {
                const float* ri = detb + (int)ord[i] * 7;
                float bxi = ri[1], byi = ri[2], bwi = ri[3], bhi = ri[4];
                float xi1 = bxi - 0.5f * bwi, xi2 = bxi + 0.5f * bwi;
                float yi1 = byi - 0.5f * bhi, yi2 = byi + 0.5f * bhi;
                float ai = bwi * bhi;
                for (int j = i + 1 + tid; j < num_obj; j += 1024) {
                    const float* rj = detb + (int)ord[j] * 7;
                    float bxj = rj[1], byj = rj[2], bwj = rj[3], bhj = rj[4];
                    float x1j = bxj - 0.5f * bwj, x2j = bxj + 0.5f * bwj;
                    float y1j = byj - 0.5f * bhj, y2j = byj + 0.5f * bhj;
                    float aj = bwj * bhj;
                    float iw = fmaxf(fminf(x2j, xi2) - fmaxf(x1j, xi1), 0.0f);
                    float ih = fmaxf(fminf(y2j, yi2) - fmaxf(y1j, yi1), 0.0f);
                    float inter = iw * ih;
                    float iou = inter / ((aj + ai) - inter);
                    if (iou >= 0.45f) sobj[j] = 0.0f;
                }
            }
            __syncthreads();
        }
    }
}

__global__ __launch_bounds__(256) void epi_kernel(
    float* __restrict__ det,
    const unsigned short* __restrict__ order_g,
    const float* __restrict__ sobj_g,
    const int* __restrict__ nobj_g)
{
#pragma clang fp contract(off)
    const int b = blockIdx.x;
    const int tid = threadIdx.x;
    float* detb = det + (size_t)b * NBOX * 7;
    const unsigned short* ord = order_g + b * NPAD;
    const float* sobj = sobj_g + b * NPAD;
    const int num_obj = nobj_g[b];

    float v0[8], v1[8], v2[8], v3[8], v4[8], v5[8], v6[8], msk[8];
#pragma unroll
    for (int c = 0; c < 8; ++c) {
        int r = tid + c * 256;
        if (r < NBOX) {
            const float* row = detb + (int)ord[r] * 7;
            float obj = row[0], bx = row[1], by = row[2], bw = row[3];
            float bh = row[4], cid = row[5], prob = row[6];
            bool keep = (r < num_obj) && (sobj[r] > 0.01f) && (r != num_obj - 1);
            float p = prob * ((prob > 0.1f) ? 1.0f : 0.0f);
            bool fin = keep && (p > 0.01f) && (bw * bw > 0.0004f);
            v0[c] = obj; v1[c] = bx; v2[c] = by; v3[c] = bw; v4[c] = bh;
            v5[c] = cid; v6[c] = p;
            msk[c] = fin ? 1.0f : 0.0f;
        }
    }
    __syncthreads();
#pragma unroll
    for (int c = 0; c < 8; ++c) {
        int r = tid + c * 256;
        if (r < NBOX) {
            float* o = detb + r * 7;
            o[0] = v0[c] * msk[c];
            o[1] = v1[c] * msk[c];
            o[2] = v2[c] * msk[c];
            o[3] = v3[c] * msk[c];
            o[4] = v4[c] * msk[c];
            o[5] = v5[c] * msk[c];
            o[6] = v6[c] * msk[c];
        }
    }
}

// ---------------------------------------------------------------------------
// Last-resort monolithic kernel (ws < WS_NEEDED).
// ---------------------------------------------------------------------------
__global__ __launch_bounds__(K2T, 1) void nms_kernel(float* __restrict__ det)
{
#pragma clang fp contract(off)
    __shared__ alignas(16) unsigned long long keys[NPAD];
    __shared__ float s_obj[NBOX];
    __shared__ unsigned short order[NBOX];
    __shared__ int num_obj_sh;

    const int b = blockIdx.x;
    const int tid = threadIdx.x;
    float* detb = det + (size_t)b * NBOX * 7;

    for (int n = tid; n < NPAD; n += K2T) {
        if (n < NBOX) {
            unsigned ob = __float_as_uint(detb[n * 7 + 0]);
            keys[n] = ((unsigned long long)ob << 32) | (unsigned long long)(2047 - n);
        } else keys[n] = 0ull;
    }
    if (tid == 0) num_obj_sh = 0;
    __syncthreads();

    for (unsigned k = 2; k <= NPAD; k <<= 1) {
        for (unsigned j = k >> 1; j > 0; j >>= 1) {
            for (unsigned idx = tid; idx < NPAD; idx += K2T) {
                unsigned ixj = idx ^ j;
                if (ixj > idx) {
                    unsigned long long av = keys[idx], bv = keys[ixj];
                    bool up = ((idx & k) == 0);
                    if (up ? (av < bv) : (av > bv)) { keys[idx] = bv; keys[ixj] = av; }
                }
            }
            __syncthreads();
        }
    }

    int cnt = 0;
    for (int r = tid; r < NBOX; r += K2T) {
        unsigned long long kk = keys[r];
        order[r] = (unsigned short)(2047u - (unsigned)(kk & 0xffffffffu));
        float ob = __uint_as_float((unsigned)(kk >> 32));
        s_obj[r] = ob;
        cnt += (ob > 0.5f) ? 1 : 0;
    }
    atomicAdd(&num_obj_sh, cnt);
    __syncthreads();
    const int num_obj = num_obj_sh;

    for (int i = 0; i < num_obj; ++i) {
        if (s_obj[i] > 0.01f) {
            const float* ri = detb + (int)order[i] * 7;
            float bxi = ri[1], byi = ri[2], bwi = ri[3], bhi = ri[4];
            float xi1 = bxi - 0.5f * bwi, xi2 = bxi + 0.5f * bwi;
            float yi1 = byi - 0.5f * bhi, yi2 = byi + 0.5f * bhi;
            float ai = bwi * bhi;
            for (int j = i + 1 + tid; j < num_obj; j += K2T) {
                const float* rj = detb + (int)order[j] * 7;
                float bxj = rj[1], byj = rj[2], bwj = rj[3], bhj = rj[4];
                float x1j = bxj - 0.5f * bwj, x2j = bxj + 0.5f * bwj;
                float y1j = byj - 0.5f * bhj, y2j = byj + 0.5f * bhj;
                float aj = bwj * bhj;
                float iw = fmaxf(fminf(x2j, xi2) - fmaxf(x1j, xi1), 0.0f);
                float ih = fmaxf(fminf(y2j, yi2) - fmaxf(y1j, yi1), 0.0f);
                float inter = iw * ih;
                float iou = inter / ((aj + ai) - inter);
                if (iou >= 0.45f) s_obj[j] = 0.0f;
            }
        }
        __syncthreads();
    }

    float v0[8], v1[8], v2[8], v3[8], v4[8], v5[8], v6[8], msk[8];
#pragma unroll
    for (int c = 0; c < 8; ++c) {
        int r = tid + c * K2T;
        if (r < NBOX) {
            const float* row = detb + (int)order[r] * 7;
            float obj = row[0], bx = row[1], by = row[2], bw = row[3];
            float bh = row[4], cid = row[5], prob = row[6];
            bool keep = (r < num_obj) && (s_obj[r] > 0.01f) && (r != num_obj - 1);
            float p = prob * ((prob > 0.1f) ? 1.0f : 0.0f);
            bool fin = keep && (p > 0.01f) && (bw * bw > 0.0004f);
            v0[c] = obj; v1[c] = bx; v2[c] = by; v3[c] = bw; v4[c] = bh;
            v5[c] = cid; v6[c] = p;
            msk[c] = fin ? 1.0f : 0.0f;
        }
    }
    __syncthreads();
#pragma unroll
    for (int c = 0; c < 8; ++c) {
        int r = tid + c * K2T;
        if (r < NBOX) {
            float* o = detb + r * 7;
            o[0] = v0[c] * msk[c]; o[1] = v1[c] * msk[c]; o[2] = v2[c] * msk[c];
            o[3] = v3[c] * msk[c]; o[4] = v4[c] * msk[c]; o[5] = v5[c] * msk[c];
            o[6] = v6[c] * msk[c];
        }
    }
}

extern "C" void kernel_launch(void* const* d_in, const int* in_sizes, int n_in,
                              void* d_out, int out_size, void* d_ws, size_t ws_size,
                              hipStream_t stream)
{
    const float* pred    = (const float*)d_in[0];
    const float* anchors = (const float*)d_in[1];
    float* out = (float*)d_out;

    int total = NBATCH * NBOX;
    int blocks = (total + 255) / 256;
    decode_kernel<<<blocks, 256, 0, stream>>>(pred, anchors, out);

    if (ws_size >= WS_NEEDED3) {
        char* ws = (char*)d_ws;
        int*                nobj  = (int*)(ws + WS_NUMOBJ_OFF);
        float*              sobj  = (float*)(ws + WS_SOBJ_OFF);
        unsigned long long* sup   = (unsigned long long*)(ws + WS_SUP_OFF);
        unsigned long long* drow  = (unsigned long long*)(ws + WS_DROW_OFF);
        float*              detw  = (float*)(ws + WS_DETW_OFF);
        sortc_kernel<<<NBATCH, 1024, 0, stream>>>(pred, out, sobj, nobj, detw);
        sup_kernel<<<NBATCH * NSPLIT, 1024, 0, stream>>>(nobj, sup, drow, detw);
        scanepi3_kernel<<<NBATCH, 256, 0, stream>>>(out, detw, sobj, nobj, sup, drow);
    } else if (ws_size >= WS_NEEDED) {
        char* ws = (char*)d_ws;
        int*            nobj  = (int*)(ws + WS_NUMOBJ_OFF);
        unsigned short* order = (unsigned short*)(ws + WS_ORDER_OFF);
        float*          sobj  = (float*)(ws + WS_SOBJ_OFF);
        sort_kernel<<<NBATCH, 1024, 0, stream>>>(out, order, sobj, nobj);
        nms4_kernel<<<NBATCH, 1024, 0, stream>>>(out, order, sobj, nobj);
        epi_kernel<<<NBATCH, 256, 0, stream>>>(out, order, sobj, nobj);
    } else {
        nms_kernel<<<NBATCH, K2T, 0, stream>>>(out);
    }
}

// Round 22
// 111.763 us; speedup vs baseline: 1.1943x; 1.0157x over previous
//
#include <hip/hip_runtime.h>

#define NUMA 5
#define NCLS 80
#define AL 85          // 80 + 4 + 1
#define HW 361         // 19*19
#define NBOX 1805      // 5*361
#define NBATCH 128
#define NPAD 2048
#define K2T 256
#define MCAP 1024      // cap on num_obj for fast path (expected ~902 +/- 21)
#define NCHUNK 16      // MCAP / 64
#define NSPLIT 8       // sup blocks per image

// ---- d_ws layout ----
#define WS_NUMOBJ_OFF 0                                  // int32 [128]
#define WS_ORDER_OFF  512                                // u16   [128][2048]
#define WS_SOBJ_OFF   (512 + NBATCH * NPAD * 2)          // f32   [128][2048]
#define WS_NEEDED     ((size_t)(WS_SOBJ_OFF + NBATCH * NPAD * 4))   // ~1.5 MB
#define WS_SUP_OFF    WS_NEEDED                          // u64 [128][16][1024]
#define WS_DROW_OFF   (WS_SUP_OFF + (size_t)NBATCH * NCHUNK * MCAP * 8)
#define WS_NEEDED2    (WS_DROW_OFF + (size_t)NBATCH * NCHUNK * 64 * 8)  // ~19.3 MB
#define WS_DETW_OFF   WS_NEEDED2                         // f32 [128][1805][7]
#define WS_NEEDED3    (WS_DETW_OFF + (size_t)NBATCH * NBOX * 7 * 4)     // ~25.8 MB

// Exact-division-compare constant: MID = (0.45f + pred(0.45f))/2 exactly.
// RN32(inter/denom) >= 0.45f  <=>  fma64(denom, MID, -inter) <= 0 (exact sign)
#define MID_CONST (30198987.0 / 67108864.0)

__device__ __forceinline__ unsigned long long bcast64(unsigned long long v, int t) {
    unsigned lo = (unsigned)__builtin_amdgcn_readlane((int)(unsigned)v, t);
    unsigned hi = (unsigned)__builtin_amdgcn_readlane((int)(unsigned)(v >> 32), t);
    return ((unsigned long long)hi << 32) | (unsigned long long)lo;
}

__device__ __forceinline__ unsigned long long shflxor64(unsigned long long v, int j) {
    unsigned lo = __shfl_xor((unsigned)v, j, 64);
    unsigned hi = __shfl_xor((unsigned)(v >> 32), j, 64);
    return ((unsigned long long)hi << 32) | (unsigned long long)lo;
}

// Reference-exact suppression test (iou >= 0.45f under IEEE f32 ref arith).
__device__ __forceinline__ bool supp_test(float4 qj, float aj, float4 qi, float ai) {
#pragma clang fp contract(off)
    float iw = fmaxf(fminf(qj.z, qi.z) - fmaxf(qj.x, qi.x), 0.0f);
    float ih = fmaxf(fminf(qj.w, qi.w) - fmaxf(qj.y, qi.y), 0.0f);
    float inter = iw * ih;
    float denom = (aj + ai) - inter;
    return fma((double)denom, MID_CONST, -(double)inter) <= 0.0;
}

// ---------------------------------------------------------------------------
// Kernel 1: decode.  pred [B, 425, 19, 19] -> det [B, 1805, 7] written to out
// ---------------------------------------------------------------------------
__global__ __launch_bounds__(256) void decode_kernel(
    const float* __restrict__ pred,
    const float* __restrict__ anchors,
    float* __restrict__ det)
{
#pragma clang fp contract(off)
    int id = blockIdx.x * blockDim.x + threadIdx.x;
    if (id >= NBATCH * NBOX) return;
    int b = id / NBOX;
    int r = id - b * NBOX;
    int a = r / HW;
    int s = r - a * HW;
    int ci = s % 19;
    int cj = s / 19;

    const float* base = pred + ((size_t)(b * (NUMA * AL) + a * AL) * HW + s);
    float tx  = base[0 * HW];
    float ty  = base[1 * HW];
    float tw  = base[2 * HW];
    float th  = base[3 * HW];
    float obj = base[4 * HW];

    float cmax = base[5 * HW];
    int karg = 0;
#pragma unroll 4
    for (int k = 1; k < NCLS; ++k) {
        float c = base[(5 + k) * HW];
        if (c > cmax) { cmax = c; karg = k; }
    }

    float bx = (tx + (float)ci) / 19.0f;
    float by = (ty + (float)cj) / 19.0f;
    float aw = anchors[2 * a];
    float ah = anchors[2 * a + 1];
    float bw = expf(tw) * (aw / 19.0f);
    float bh = expf(th) * (ah / 19.0f);
    float prob = cmax * obj;
    float cid  = (float)karg;

    float* o = det + (size_t)(b * NBOX + r) * 7;
    o[0] = obj; o[1] = bx; o[2] = by; o[3] = bw; o[4] = bh; o[5] = cid; o[6] = prob;
}

// ---------------------------------------------------------------------------
// Kernel 2 (tier 3): top-K sort, hybrid shuffle/LDS bitonic.
// ---------------------------------------------------------------------------
__global__ __launch_bounds__(1024) void sortc_kernel(
    const float* __restrict__ pred,
    const float* __restrict__ det,
    float* __restrict__ sobj_g,
    int* __restrict__ nobj_g,
    float* __restrict__ detws)
{
    __shared__ unsigned long long keys[NPAD];
    __shared__ int c0s[16], c1s[16];
    __shared__ int ex0s[16], ex1s[16];
    __shared__ int cnt_sh, totA_sh;
    const int b = blockIdx.x;
    const int tid = threadIdx.x;
    const int lane = tid & 63;
    const int wv = tid >> 6;
    const float* detb = det + (size_t)b * NBOX * 7;
    const float* predb = pred + (size_t)b * (NUMA * AL) * HW;

    int r0 = tid;
    int r1 = tid + 1024;
    int a0 = r0 / HW, s0 = r0 - a0 * HW;
    float obj0 = predb[(a0 * AL + 4) * HW + s0];
    float obj1 = -1.0f;
    if (r1 < NBOX) {
        int a1 = r1 / HW, s1 = r1 - a1 * HW;
        obj1 = predb[(a1 * AL + 4) * HW + s1];
    }
    bool p0 = obj0 > 0.5f;
    bool p1 = (r1 < NBOX) && (obj1 > 0.5f);
    unsigned long long m0 = __ballot(p0);
    unsigned long long m1 = __ballot(p1);
    if (lane == 0) { c0s[wv] = __builtin_popcountll(m0); c1s[wv] = __builtin_popcountll(m1); }
    __syncthreads();
    if (tid == 0) {
        int acc = 0;
        for (int w = 0; w < 16; ++w) { ex0s[w] = acc; acc += c0s[w]; }
        totA_sh = acc;
        for (int w = 0; w < 16; ++w) { ex1s[w] = acc; acc += c1s[w]; }
        cnt_sh = acc;
    }
    __syncthreads();
    const int cnt = cnt_sh;
    unsigned long long ltm = (1ull << lane) - 1ull;

    if (cnt <= MCAP) {
        if (p0) {
            int pos = ex0s[wv] + __builtin_popcountll(m0 & ltm);
            keys[pos] = ((unsigned long long)__float_as_uint(obj0) << 32)
                      | (unsigned long long)(2047 - r0);
        }
        if (p1) {
            int pos = ex1s[wv] + __builtin_popcountll(m1 & ltm);
            keys[pos] = ((unsigned long long)__float_as_uint(obj1) << 32)
                      | (unsigned long long)(2047 - r1);
        }
        if (tid >= cnt) keys[tid] = 0ull;
        __syncthreads();

        // --- hybrid bitonic over 1024 keys, descending; key in register ---
        unsigned long long key = keys[tid];
        for (unsigned k = 2; k <= 1024; k <<= 1) {
            for (unsigned j = k >> 1; j > 0; j >>= 1) {
                unsigned long long other;
                if (j >= 64) {
                    __syncthreads();
                    keys[tid] = key;
                    __syncthreads();
                    other = keys[tid ^ j];
                } else {
                    other = shflxor64(key, (int)j);
                }
                bool lower = ((tid & j) == 0);
                bool up = ((tid & k) == 0);
                bool keepmax = (lower == up);
                unsigned long long mx = (key > other) ? key : other;
                unsigned long long mn = (key > other) ? other : key;
                key = keepmax ? mx : mn;
            }
        }

        // --- outputs directly from register key ---
        float* dst = detws + ((size_t)b * NBOX + tid) * 7;
        if (tid < cnt) {
            int idx = 2047 - (int)(unsigned)(key & 0xffffffffu);
            sobj_g[b * NPAD + tid] = __uint_as_float((unsigned)(key >> 32));
            const float* src = detb + idx * 7;
#pragma unroll
            for (int q = 0; q < 7; ++q) dst[q] = src[q];
        } else {
            sobj_g[b * NPAD + tid] = 0.0f;
#pragma unroll
            for (int q = 0; q < 7; ++q) dst[q] = 0.0f;
        }
        sobj_g[b * NPAD + 1024 + tid] = 0.0f;
        if (tid == 0) nobj_g[b] = cnt;
    } else {
        // full-sort fallback (statistically unreachable)
        keys[r0] = ((unsigned long long)__float_as_uint(obj0) << 32)
                 | (unsigned long long)(2047 - r0);
        keys[r1] = (r1 < NBOX)
                 ? (((unsigned long long)__float_as_uint(obj1) << 32)
                    | (unsigned long long)(2047 - r1))
                 : 0ull;
        __syncthreads();
        for (unsigned k = 2; k <= NPAD; k <<= 1) {
            for (unsigned j = k >> 1; j > 0; j >>= 1) {
                for (unsigned idx = tid; idx < NPAD; idx += 1024) {
                    unsigned ixj = idx ^ j;
                    if (ixj > idx) {
                        unsigned long long av = keys[idx], bv = keys[ixj];
                        bool up = ((idx & k) == 0);
                        if (up ? (av < bv) : (av > bv)) { keys[idx] = bv; keys[ixj] = av; }
                    }
                }
                __syncthreads();
            }
        }
        for (int r = tid; r < NBOX; r += 1024) {
            unsigned long long kk = keys[r];
            int idx = 2047 - (int)(unsigned)(kk & 0xffffffffu);
            sobj_g[b * NPAD + r] = __uint_as_float((unsigned)(kk >> 32));
            const float* src = detb + idx * 7;
            float* dst = detws + ((size_t)b * NBOX + r) * 7;
#pragma unroll
            for (int q = 0; q < 7; ++q) dst[q] = src[q];
        }
        for (int r = NBOX + tid; r < NPAD; r += 1024) sobj_g[b * NPAD + r] = 0.0f;
        if (tid == 0) nobj_g[b] = cnt;
    }
}

// ---------------------------------------------------------------------------
// Kernel (fallback tiers): per-image stable bitonic sort (desc by obj).
// ---------------------------------------------------------------------------
__global__ __launch_bounds__(1024) void sort_kernel(
    const float* __restrict__ det,
    unsigned short* __restrict__ order_g,
    float* __restrict__ sobj_g,
    int* __restrict__ nobj_g)
{
    __shared__ unsigned long long keys[NPAD];
    __shared__ int cnt_sh;
    const int b = blockIdx.x;
    const int tid = threadIdx.x;
    const float* detb = det + (size_t)b * NBOX * 7;

    for (int n = tid; n < NPAD; n += 1024) {
        keys[n] = (n < NBOX)
            ? (((unsigned long long)__float_as_uint(detb[n * 7]) << 32)
               | (unsigned long long)(2047 - n))
            : 0ull;
    }
    if (tid == 0) cnt_sh = 0;
    __syncthreads();

    for (unsigned k = 2; k <= NPAD; k <<= 1) {
        for (unsigned j = k >> 1; j > 0; j >>= 1) {
            for (unsigned idx = tid; idx < NPAD; idx += 1024) {
                unsigned ixj = idx ^ j;
                if (ixj > idx) {
                    unsigned long long av = keys[idx], bv = keys[ixj];
                    bool up = ((idx & k) == 0);
                    if (up ? (av < bv) : (av > bv)) { keys[idx] = bv; keys[ixj] = av; }
                }
            }
            __syncthreads();
        }
    }

    int cnt = 0;
    for (int r = tid; r < NBOX; r += 1024) {
        unsigned long long kk = keys[r];
        int idx = 2047 - (int)(unsigned)(kk & 0xffffffffu);
        order_g[b * NPAD + r] = (unsigned short)idx;
        float ob = __uint_as_float((unsigned)(kk >> 32));
        sobj_g[b * NPAD + r] = ob;
        cnt += (ob > 0.5f) ? 1 : 0;
    }
    atomicAdd(&cnt_sh, cnt);
    __syncthreads();
    if (tid == 0) nobj_g[b] = cnt_sh;
}

// ---------------------------------------------------------------------------
// Kernel 3: suppression-matrix build (best config: LDS-staged boxes,
// NSPLIT=8 balanced tiles, unroll 8, pure-f64 exact test).
// ---------------------------------------------------------------------------
__global__ __launch_bounds__(1024) void sup_kernel(
    const int* __restrict__ nobj_g,
    unsigned long long* __restrict__ sup_g,
    unsigned long long* __restrict__ drow_g,
    const float* __restrict__ detws)
{
#pragma clang fp contract(off)
    __shared__ float4 QS[MCAP];                          // 16 KB
    __shared__ float  AS[MCAP];                          // 4 KB
    const int bb = blockIdx.x;
    const int b = bb / NSPLIT;
    const int part = bb - b * NSPLIT;
    const int tid = threadIdx.x;
    const int lane = tid & 63;
    const int wv = tid >> 6;
    const int num_obj = nobj_g[b];
    if (num_obj > MCAP) return;                          // fallback handles
    const int M = num_obj;
    const int Mc = (M + 63) >> 6;                        // active chunks
    const int Atiles = Mc * (Mc + 1) / 2;                // active tiles
    const int NW = 16 * NSPLIT;                          // global waves/image

    {
        const float* src = detws + ((size_t)b * NBOX + tid) * 7;   // coalesced
        float bx = src[1], by = src[2], bw = src[3], bh = src[4];
        QS[tid] = make_float4(bx - 0.5f * bw, by - 0.5f * bh,
                              bx + 0.5f * bw, by + 0.5f * bh);
        AS[tid] = bw * bh;
    }
    __syncthreads();

    const int gw = part * 16 + wv;                       // 0..NW-1
    const int ks = (gw * Atiles) / NW;
    const int ke = ((gw + 1) * Atiles) / NW;
    for (int k = ks; k < ke; ++k) {
        int c2 = 0;
        while ((c2 + 1) * (c2 + 2) / 2 <= k) ++c2;       // tile -> (c2, cc<=c2)
        int cc = k - c2 * (c2 + 1) / 2;
        int j = c2 * 64 + lane;
        float4 qj = QS[j];
        float  aj = AS[j];
        unsigned long long w = 0ull;
        if (cc == c2) {
            unsigned long long myrow = 0ull;
            for (int t = 0; t < 64; ++t) {
                bool supp = supp_test(qj, aj, QS[cc * 64 + t], AS[cc * 64 + t])
                            && (t < lane);
                unsigned long long bb2 = __ballot(supp);
                w |= supp ? (1ull << t) : 0ull;
                if (lane == t) myrow = bb2;
            }
            drow_g[((size_t)b * NCHUNK + cc) * 64 + lane] = myrow;
        } else {
#pragma unroll 8
            for (int t = 0; t < 64; ++t) {
                bool supp = supp_test(qj, aj, QS[cc * 64 + t], AS[cc * 64 + t]);
                w |= supp ? (1ull << t) : 0ull;
            }
        }
        sup_g[((size_t)b * NCHUNK + cc) * MCAP + j] = w;
    }
}

// ---------------------------------------------------------------------------
// Kernel 4 (tier 3): fused scan + epilogue, 1024 threads/image (16 waves for
// the memory-bound staging/epilogue phases; LDS 144 KB -> 1 block/CU either
// way, so the extra waves are free). Wave 0 runs the serial scan.
// ---------------------------------------------------------------------------
__global__ __launch_bounds__(1024) void scanepi3_kernel(
    float* __restrict__ det,
    const float* __restrict__ detws,
    const float* __restrict__ sobj_g,
    const int* __restrict__ nobj_g,
    const unsigned long long* __restrict__ sup_g,
    const unsigned long long* __restrict__ drow_g)
{
#pragma clang fp contract(off)
    __shared__ unsigned long long SUPL[NCHUNK][MCAP];    // 128 KB
    __shared__ unsigned long long DR[NCHUNK][64];        // 8 KB
    __shared__ float sobj_l[NPAD];                       // 8 KB
    const int b = blockIdx.x;
    const int tid = threadIdx.x;
    const int lane = tid & 63;
    float* detb = det + (size_t)b * NBOX * 7;
    const float* dws = detws + (size_t)b * NBOX * 7;
    const int num_obj = nobj_g[b];
    const int M = (num_obj < MCAP) ? num_obj : MCAP;
    const int Mc = (M + 63) >> 6;

#pragma unroll
    for (int c = 0; c < 2; ++c)
        sobj_l[tid + c * 1024] = sobj_g[b * NPAD + tid + c * 1024];

    if (num_obj <= MCAP) {
        const unsigned long long* supb = sup_g + (size_t)b * NCHUNK * MCAP;
        // stage the active chunks: Mc strips of 1024 u64
        for (int i = 0; i < Mc; ++i)
            ((unsigned long long*)SUPL)[tid + i * 1024] = supb[tid + i * 1024];
        ((unsigned long long*)DR)[tid] = drow_g[(size_t)b * NCHUNK * 64 + tid];
        __syncthreads();

        if (tid < 64) {
            unsigned rm = 0u;                  // bit c = my box in chunk c dead
            for (int c = 0; c < NCHUNK && c * 64 < M; ++c) {
                int rem_in = M - c * 64;
                unsigned long long cmask =
                    (rem_in >= 64) ? ~0ull : ((1ull << rem_in) - 1ull);
                unsigned long long deadw = __ballot((rm >> c) & 1u);
                unsigned long long rowreg = DR[c][lane];
                unsigned long long rem = cmask & ~deadw;
                const unsigned long long rem0 = rem;
                unsigned long long S = 0ull;   // survivors of chunk c
                while (rem) {
                    int t = (int)__builtin_ctzll(rem);
                    S |= (1ull << t);
                    unsigned long long row_t = bcast64(rowreg, t);
                    rem &= ~row_t;
                    rem &= ~(1ull << t);
                }
                unsigned long long deadnew = rem0 & ~S;
                rm |= (unsigned)((deadnew >> lane) & 1ull) << c;
                for (int c2 = c + 1; c2 < NCHUNK && c2 * 64 < M; ++c2) {
                    unsigned long long w2 = SUPL[c][c2 * 64 + lane];
                    rm |= ((w2 & S) != 0ull) ? (1u << c2) : 0u;
                }
            }
#pragma unroll
            for (int c2 = 0; c2 < NCHUNK; ++c2) {
                int j = c2 * 64 + lane;
                if (j < M && ((rm >> c2) & 1u)) sobj_l[j] = 0.0f;
            }
        }
        __syncthreads();
    } else {
        __syncthreads();
        // fallback: serial greedy over coalesced sorted rows
        for (int i = 0; i < num_obj; ++i) {
            if (sobj_l[i] > 0.01f) {
                const float* ri = dws + i * 7;
                float bxi = ri[1], byi = ri[2], bwi = ri[3], bhi = ri[4];
                float xi1 = bxi - 0.5f * bwi, xi2 = bxi + 0.5f * bwi;
                float yi1 = byi - 0.5f * bhi, yi2 = byi + 0.5f * bhi;
                float ai = bwi * bhi;
                for (int j = i + 1 + tid; j < num_obj; j += 1024) {
                    const float* rj = dws + j * 7;
                    float bxj = rj[1], byj = rj[2], bwj = rj[3], bhj = rj[4];
                    float x1j = bxj - 0.5f * bwj, x2j = bxj + 0.5f * bwj;
                    float y1j = byj - 0.5f * bhj, y2j = byj + 0.5f * bhj;
                    float aj = bwj * bhj;
                    float iw = fmaxf(fminf(x2j, xi2) - fmaxf(x1j, xi1), 0.0f);
                    float ih = fmaxf(fminf(y2j, yi2) - fmaxf(y1j, yi1), 0.0f);
                    float inter = iw * ih;
                    float iou = inter / ((aj + ai) - inter);
                    if (iou >= 0.45f) sobj_l[j] = 0.0f;
                }
            }
            __syncthreads();
        }
    }

    // --- epilogue: rows < num_obj from detws; rows >= num_obj are zeros ---
#pragma unroll
    for (int c = 0; c < 2; ++c) {
        int r = tid + c * 1024;
        if (r < NBOX) {
            float* o = detb + r * 7;
            if (r < num_obj) {
                const float* src = dws + r * 7;
                float obj = src[0], bx = src[1], by = src[2], bw = src[3];
                float bh = src[4], cid = src[5], prob = src[6];
                float s = sobj_l[r];
                bool keep = (s > 0.01f) && (r != num_obj - 1);
                float p = prob * ((prob > 0.1f) ? 1.0f : 0.0f);
                bool fin = keep && (p > 0.01f) && (bw * bw > 0.0004f);
                float m = fin ? 1.0f : 0.0f;
                o[0] = obj * m; o[1] = bx * m; o[2] = by * m; o[3] = bw * m;
                o[4] = bh * m; o[5] = cid * m; o[6] = p * m;
            } else {
                o[0] = 0.0f; o[1] = 0.0f; o[2] = 0.0f; o[3] = 0.0f;
                o[4] = 0.0f; o[5] = 0.0f; o[6] = 0.0f;
            }
        }
    }
}

// ---------------------------------------------------------------------------
// Tier-1 fallback (1.5MB <= ws < 25.8MB): monolithic two-phase NMS + epi.
// ---------------------------------------------------------------------------
__global__ __launch_bounds__(1024, 1) void nms4_kernel(
    const float* __restrict__ det,
    const unsigned short* __restrict__ order_g,
    float* __restrict__ sobj_g,
    const int* __restrict__ nobj_g)
{
#pragma clang fp contract(off)
    __shared__ float4 QS[MCAP];
    __shared__ float  AS[MCAP];
    __shared__ unsigned long long SUP[NCHUNK][MCAP];
    __shared__ unsigned long long DROW[NCHUNK][64];
    const int b = blockIdx.x;
    const int tid = threadIdx.x;
    const int lane = tid & 63;
    const int wv = tid >> 6;
    const float* detb = det + (size_t)b * NBOX * 7;
    const unsigned short* ord = order_g + b * NPAD;
    float* sobj = sobj_g + b * NPAD;
    const int num_obj = nobj_g[b];
    const int M = (num_obj < MCAP) ? num_obj : MCAP;

    if (num_obj <= MCAP) {
        {
            const float* row = detb + (int)ord[tid] * 7;
            float bx = row[1], by = row[2], bw = row[3], bh = row[4];
            QS[tid] = make_float4(bx - 0.5f * bw, by - 0.5f * bh,
                                  bx + 0.5f * bw, by + 0.5f * bh);
            AS[tid] = bw * bh;
        }
        __syncthreads();

        for (int k = wv; k < 136; k += 16) {
            int c2 = 0;
            while ((c2 + 1) * (c2 + 2) / 2 <= k) ++c2;
            int cc = k - c2 * (c2 + 1) / 2;
            if (c2 * 64 < M) {
                int j = c2 * 64 + lane;
                float4 qj = QS[j];
                float  aj = AS[j];
                unsigned long long w = 0ull;
                if (cc == c2) {
                    unsigned long long myrow = 0ull;
                    for (int t = 0; t < 64; ++t) {
                        bool supp = supp_test(qj, aj, QS[cc * 64 + t], AS[cc * 64 + t])
                                    && (t < lane);
                        unsigned long long bb = __ballot(supp);
                        w |= supp ? (1ull << t) : 0ull;
                        if (lane == t) myrow = bb;
                    }
                    DROW[cc][lane] = myrow;
                } else {
#pragma unroll 8
                    for (int t = 0; t < 64; ++t) {
                        bool supp = supp_test(qj, aj, QS[cc * 64 + t], AS[cc * 64 + t]);
                        w |= supp ? (1ull << t) : 0ull;
                    }
                }
                SUP[cc][j] = w;
            }
        }
        __syncthreads();

        if (wv == 0) {
            unsigned rm = 0u;
            for (int c = 0; c < NCHUNK && c * 64 < M; ++c) {
                int rem_in = M - c * 64;
                unsigned long long cmask =
                    (rem_in >= 64) ? ~0ull : ((1ull << rem_in) - 1ull);
                unsigned long long deadw = __ballot((rm >> c) & 1u);
                unsigned long long rowreg = DROW[c][lane];
                unsigned long long rem = cmask & ~deadw;
                const unsigned long long rem0 = rem;
                unsigned long long S = 0ull;
                while (rem) {
                    int t = (int)__builtin_ctzll(rem);
                    S |= (1ull << t);
                    unsigned long long row_t = bcast64(rowreg, t);
                    rem &= ~row_t;
                    rem &= ~(1ull << t);
                }
                unsigned long long deadnew = rem0 & ~S;
                rm |= (unsigned)((deadnew >> lane) & 1ull) << c;
                for (int c2 = c + 1; c2 < NCHUNK && c2 * 64 < M; ++c2) {
                    unsigned long long w2 = SUP[c][c2 * 64 + lane];
                    rm |= ((w2 & S) != 0ull) ? (1u << c2) : 0u;
                }
            }
            for (int c2 = 0; c2 < NCHUNK; ++c2) {
                int j = c2 * 64 + lane;
                if (j < M && ((rm >> c2) & 1u)) sobj[j] = 0.0f;
            }
        }
    } else {
        for (int i = 0; i < num_obj; ++i) {
            if (sobj[i] > 0.01f) {
                const float* ri = detb + (int)ord[i] * 7;
                float bxi = ri[1], byi = ri[2], bwi = ri[3], bhi = ri[4];
                float xi1 = bxi - 0.5f * bwi, xi2 = bxi + 0.5f * bwi;
                float yi1 = byi - 0.5f * bhi, yi2 = byi + 0.5f * bhi;
                float ai = bwi * bhi;
                for (int j = i + 1 + tid; j < num_obj; j += 1024) {
                    const float* rj = detb + (int)ord[j] * 7;
                    float bxj = rj[1], byj = rj[2], bwj = rj[3], bhj = rj[4];
                    float x1j = bxj - 0.5f * bwj, x2j = bxj + 0.5f * bwj;
                    float y1j = byj - 0.5f * bhj, y2j = byj + 0.5f * bhj;
                    float aj = bwj * bhj;
                    float iw = fmaxf(fminf(x2j, xi2) - fmaxf(x1j, xi1), 0.0f);
                    float ih = fmaxf(fminf(y2j, yi2) - fmaxf(y1j, yi1), 0.0f);
                    float inter = iw * ih;
                    float iou = inter / ((aj + ai) - inter);
                    if (iou >= 0.45f) sobj[j] = 0.0f;
                }
            }
            __syncthreads();
        }
    }
}

__global__ __launch_bounds__(256) void epi_kernel(
    float* __restrict__ det,
    const unsigned short* __restrict__ order_g,
    const float* __restrict__ sobj_g,
    const int* __restrict__ nobj_g)
{
#pragma clang fp contract(off)
    const int b = blockIdx.x;
    const int tid = threadIdx.x;
    float* detb = det + (size_t)b * NBOX * 7;
    const unsigned short* ord = order_g + b * NPAD;
    const float* sobj = sobj_g + b * NPAD;
    const int num_obj = nobj_g[b];

    float v0[8], v1[8], v2[8], v3[8], v4[8], v5[8], v6[8], msk[8];
#pragma unroll
    for (int c = 0; c < 8; ++c) {
        int r = tid + c * 256;
        if (r < NBOX) {
            const float* row = detb + (int)ord[r] * 7;
            float obj = row[0], bx = row[1], by = row[2], bw = row[3];
            float bh = row[4], cid = row[5], prob = row[6];
            bool keep = (r < num_obj) && (sobj[r] > 0.01f) && (r != num_obj - 1);
            float p = prob * ((prob > 0.1f) ? 1.0f : 0.0f);
            bool fin = keep && (p > 0.01f) && (bw * bw > 0.0004f);
            v0[c] = obj; v1[c] = bx; v2[c] = by; v3[c] = bw; v4[c] = bh;
            v5[c] = cid; v6[c] = p;
            msk[c] = fin ? 1.0f : 0.0f;
        }
    }
    __syncthreads();
#pragma unroll
    for (int c = 0; c < 8; ++c) {
        int r = tid + c * 256;
        if (r < NBOX) {
            float* o = detb + r * 7;
            o[0] = v0[c] * msk[c];
            o[1] = v1[c] * msk[c];
            o[2] = v2[c] * msk[c];
            o[3] = v3[c] * msk[c];
            o[4] = v4[c] * msk[c];
            o[5] = v5[c] * msk[c];
            o[6] = v6[c] * msk[c];
        }
    }
}

// ---------------------------------------------------------------------------
// Last-resort monolithic kernel (ws < WS_NEEDED).
// ---------------------------------------------------------------------------
__global__ __launch_bounds__(K2T, 1) void nms_kernel(float* __restrict__ det)
{
#pragma clang fp contract(off)
    __shared__ alignas(16) unsigned long long keys[NPAD];
    __shared__ float s_obj[NBOX];
    __shared__ unsigned short order[NBOX];
    __shared__ int num_obj_sh;

    const int b = blockIdx.x;
    const int tid = threadIdx.x;
    float* detb = det + (size_t)b * NBOX * 7;

    for (int n = tid; n < NPAD; n += K2T) {
        if (n < NBOX) {
            unsigned ob = __float_as_uint(detb[n * 7 + 0]);
            keys[n] = ((unsigned long long)ob << 32) | (unsigned long long)(2047 - n);
        } else keys[n] = 0ull;
    }
    if (tid == 0) num_obj_sh = 0;
    __syncthreads();

    for (unsigned k = 2; k <= NPAD; k <<= 1) {
        for (unsigned j = k >> 1; j > 0; j >>= 1) {
            for (unsigned idx = tid; idx < NPAD; idx += K2T) {
                unsigned ixj = idx ^ j;
                if (ixj > idx) {
                    unsigned long long av = keys[idx], bv = keys[ixj];
                    bool up = ((idx & k) == 0);
                    if (up ? (av < bv) : (av > bv)) { keys[idx] = bv; keys[ixj] = av; }
                }
            }
            __syncthreads();
        }
    }

    int cnt = 0;
    for (int r = tid; r < NBOX; r += K2T) {
        unsigned long long kk = keys[r];
        order[r] = (unsigned short)(2047u - (unsigned)(kk & 0xffffffffu));
        float ob = __uint_as_float((unsigned)(kk >> 32));
        s_obj[r] = ob;
        cnt += (ob > 0.5f) ? 1 : 0;
    }
    atomicAdd(&num_obj_sh, cnt);
    __syncthreads();
    const int num_obj = num_obj_sh;

    for (int i = 0; i < num_obj; ++i) {
        if (s_obj[i] > 0.01f) {
            const float* ri = detb + (int)order[i] * 7;
            float bxi = ri[1], byi = ri[2], bwi = ri[3], bhi = ri[4];
            float xi1 = bxi - 0.5f * bwi, xi2 = bxi + 0.5f * bwi;
            float yi1 = byi - 0.5f * bhi, yi2 = byi + 0.5f * bhi;
            float ai = bwi * bhi;
            for (int j = i + 1 + tid; j < num_obj; j += K2T) {
                const float* rj = detb + (int)order[j] * 7;
                float bxj = rj[1], byj = rj[2], bwj = rj[3], bhj = rj[4];
                float x1j = bxj - 0.5f * bwj, x2j = bxj + 0.5f * bwj;
                float y1j = byj - 0.5f * bhj, y2j = byj + 0.5f * bhj;
                float aj = bwj * bhj;
                float iw = fmaxf(fminf(x2j, xi2) - fmaxf(x1j, xi1), 0.0f);
                float ih = fmaxf(fminf(y2j, yi2) - fmaxf(y1j, yi1), 0.0f);
                float inter = iw * ih;
                float iou = inter / ((aj + ai) - inter);
                if (iou >= 0.45f) s_obj[j] = 0.0f;
            }
        }
        __syncthreads();
    }

    float v0[8], v1[8], v2[8], v3[8], v4[8], v5[8], v6[8], msk[8];
#pragma unroll
    for (int c = 0; c < 8; ++c) {
        int r = tid + c * K2T;
        if (r < NBOX) {
            const float* row = detb + (int)order[r] * 7;
            float obj = row[0], bx = row[1], by = row[2], bw = row[3];
            float bh = row[4], cid = row[5], prob = row[6];
            bool keep = (r < num_obj) && (s_obj[r] > 0.01f) && (r != num_obj - 1);
            float p = prob * ((prob > 0.1f) ? 1.0f : 0.0f);
            bool fin = keep && (p > 0.01f) && (bw * bw > 0.0004f);
            v0[c] = obj; v1[c] = bx; v2[c] = by; v3[c] = bw; v4[c] = bh;
            v5[c] = cid; v6[c] = p;
            msk[c] = fin ? 1.0f : 0.0f;
        }
    }
    __syncthreads();
#pragma unroll
    for (int c = 0; c < 8; ++c) {
        int r = tid + c * K2T;
        if (r < NBOX) {
            float* o = detb + r * 7;
            o[0] = v0[c] * msk[c]; o[1] = v1[c] * msk[c]; o[2] = v2[c] * msk[c];
            o[3] = v3[c] * msk[c]; o[4] = v4[c] * msk[c]; o[5] = v5[c] * msk[c];
            o[6] = v6[c] * msk[c];
        }
    }
}

extern "C" void kernel_launch(void* const* d_in, const int* in_sizes, int n_in,
                              void* d_out, int out_size, void* d_ws, size_t ws_size,
                              hipStream_t stream)
{
    const float* pred    = (const float*)d_in[0];
    const float* anchors = (const float*)d_in[1];
    float* out = (float*)d_out;

    int total = NBATCH * NBOX;
    int blocks = (total + 255) / 256;
    decode_kernel<<<blocks, 256, 0, stream>>>(pred, anchors, out);

    if (ws_size >= WS_NEEDED3) {
        char* ws = (char*)d_ws;
        int*                nobj  = (int*)(ws + WS_NUMOBJ_OFF);
        float*              sobj  = (float*)(ws + WS_SOBJ_OFF);
        unsigned long long* sup   = (unsigned long long*)(ws + WS_SUP_OFF);
        unsigned long long* drow  = (unsigned long long*)(ws + WS_DROW_OFF);
        float*              detw  = (float*)(ws + WS_DETW_OFF);
        sortc_kernel<<<NBATCH, 1024, 0, stream>>>(pred, out, sobj, nobj, detw);
        sup_kernel<<<NBATCH * NSPLIT, 1024, 0, stream>>>(nobj, sup, drow, detw);
        scanepi3_kernel<<<NBATCH, 1024, 0, stream>>>(out, detw, sobj, nobj, sup, drow);
    } else if (ws_size >= WS_NEEDED) {
        char* ws = (char*)d_ws;
        int*            nobj  = (int*)(ws + WS_NUMOBJ_OFF);
        unsigned short* order = (unsigned short*)(ws + WS_ORDER_OFF);
        float*          sobj  = (float*)(ws + WS_SOBJ_OFF);
        sort_kernel<<<NBATCH, 1024, 0, stream>>>(out, order, sobj, nobj);
        nms4_kernel<<<NBATCH, 1024, 0, stream>>>(out, order, sobj, nobj);
        epi_kernel<<<NBATCH, 256, 0, stream>>>(out, order, sobj, nobj);
    } else {
        nms_kernel<<<NBATCH, K2T, 0, stream>>>(out);
    }
}